// Round 2
// baseline (293.624 us; speedup 1.0000x reference)
//
#include <hip/hip_runtime.h>
#include <hip/hip_bf16.h>

#define B_   2
#define S_   2048
#define DM   1024
#define NH   16
#define DKH  64
#define Mdim 4096
#define Ndim 1024
#define Kdim 1024

typedef __attribute__((ext_vector_type(8))) short bf16x8;
typedef __attribute__((ext_vector_type(4))) short bf16x4;
typedef __attribute__((ext_vector_type(4))) float f32x4;

__device__ __forceinline__ short f2b(float x) {
  union { __hip_bfloat16 h; short s; } u;
  u.h = __float2bfloat16(x);
  return u.s;
}

__device__ __forceinline__ unsigned pack_bf16(float lo, float hi) {
  return (unsigned)(unsigned short)f2b(lo) | ((unsigned)(unsigned short)f2b(hi) << 16);
}

// async global->LDS, 16 B/lane; LDS dst = wave-uniform base + lane*16
__device__ __forceinline__ void async_copy16(const void* g, void* l) {
  __builtin_amdgcn_global_load_lds(
      (const __attribute__((address_space(1))) unsigned int*)g,
      (__attribute__((address_space(3))) unsigned int*)l, 16, 0, 0);
}

// ---------------------------------------------------------------------------
// Batched fp32 -> bf16 conversion (7 tensors, one launch).
struct Cvt7 {
  const float* src[7];
  ushort* dst[7];
  int n[7];
};

__global__ __launch_bounds__(256) void cvt_all(Cvt7 c) {
  const int ten = blockIdx.y;
  const int base = (blockIdx.x * 256 + threadIdx.x) * 8;
  if (base >= c.n[ten]) return;
  const float* s = c.src[ten] + base;
  float4 a = *(const float4*)s;
  float4 b = *(const float4*)(s + 4);
  bf16x8 r;
  r[0] = f2b(a.x); r[1] = f2b(a.y); r[2] = f2b(a.z); r[3] = f2b(a.w);
  r[4] = f2b(b.x); r[5] = f2b(b.y); r[6] = f2b(b.z); r[7] = f2b(b.w);
  *(bf16x8*)(c.dst[ten] + base) = r;
}

// ---------------------------------------------------------------------------
// Pack int32 mask -> 1 bit/key. mb[(b*S + q)*32 + k/64], bit j = key 64w+j.
__global__ __launch_bounds__(256) void mask_bits(const int* __restrict__ m,
                                                 unsigned long long* __restrict__ mb) {
  const size_t i = (size_t)blockIdx.x * 256 + threadIdx.x;
  const unsigned long long bits = __ballot(m[i] != 0);
  if ((threadIdx.x & 63) == 0) mb[i >> 6] = bits;
}

// ---------------------------------------------------------------------------
__device__ __forceinline__ void gstore(float* C, size_t i, float v) { C[i] = v; }
__device__ __forceinline__ void gstore(ushort* C, size_t i, float v) { C[i] = (ushort)f2b(v); }

// m97-structure core: C[4096,1024] = A@W^T + bias, *scale. 128x128 tile,
// BK=32, LDS via global_load_lds(16B). 4 waves 2x2; wave = 64x64 (4x4 frags).
// vt=1: write head-transposed [b][h][d][s] (for V).
template <typename OutT>
__device__ __forceinline__ void gemm_core(const ushort* __restrict__ A,
                                          const ushort* __restrict__ W,
                                          const float* __restrict__ bias,
                                          OutT* __restrict__ C, float scale, int vt,
                                          ushort* a_s, ushort* b_s) {
  const int t = threadIdx.x;
  const int w = t >> 6, lane = t & 63;
  const int quad = lane >> 4, r16 = lane & 15;
  const int wr = w >> 1, wc = w & 1;
  const int row0 = blockIdx.x * 128, col0 = blockIdx.y * 128;

  const int sr = t >> 2, sc = (t & 3) * 8;
  const ushort* Ag0 = A + (size_t)(row0 + sr) * Kdim + sc;
  const ushort* Ag1 = Ag0 + (size_t)64 * Kdim;
  const ushort* Wg0 = W + (size_t)(col0 + sr) * Kdim + sc;
  const ushort* Wg1 = Wg0 + (size_t)64 * Kdim;
  ushort* al0 = a_s + (w * 16) * 32;
  ushort* al1 = a_s + (64 + w * 16) * 32;
  ushort* bl0 = b_s + (w * 16) * 32;
  ushort* bl1 = b_s + (64 + w * 16) * 32;

  f32x4 acc[4][4];
#pragma unroll
  for (int mt = 0; mt < 4; ++mt)
#pragma unroll
    for (int nt = 0; nt < 4; ++nt) acc[mt][nt] = (f32x4){0.f, 0.f, 0.f, 0.f};

  for (int k0 = 0; k0 < Kdim; k0 += 32) {
    __syncthreads();
    async_copy16(Ag0 + k0, al0);
    async_copy16(Ag1 + k0, al1);
    async_copy16(Wg0 + k0, bl0);
    async_copy16(Wg1 + k0, bl1);
    __syncthreads();

    bf16x8 af[4], bfr[4];
#pragma unroll
    for (int mt = 0; mt < 4; ++mt)
      af[mt] = *(const bf16x8*)&a_s[(wr * 64 + mt * 16 + r16) * 32 + quad * 8];
#pragma unroll
    for (int nt = 0; nt < 4; ++nt)
      bfr[nt] = *(const bf16x8*)&b_s[(wc * 64 + nt * 16 + r16) * 32 + quad * 8];
#pragma unroll
    for (int mt = 0; mt < 4; ++mt)
#pragma unroll
      for (int nt = 0; nt < 4; ++nt)
        acc[mt][nt] = __builtin_amdgcn_mfma_f32_16x16x32_bf16(af[mt], bfr[nt],
                                                              acc[mt][nt], 0, 0, 0);
  }

#pragma unroll
  for (int mt = 0; mt < 4; ++mt) {
#pragma unroll
    for (int nt = 0; nt < 4; ++nt) {
      const int col = col0 + wc * 64 + nt * 16 + r16;
      const float bv = bias[col];
      const int rowb = row0 + wr * 64 + mt * 16 + quad * 4;
#pragma unroll
      for (int i = 0; i < 4; ++i) {
        const float v = (acc[mt][nt][i] + bv) * scale;
        if (vt) {
          const int row = rowb + i;
          const int bb = row >> 11, ss = row & (S_ - 1);   // row = b*S + s
          const int hh = col >> 6, dd = col & 63;          // col = h*64 + d
          gstore(C, (((size_t)bb * NH + hh) * 64 + dd) * S_ + ss, v);
        } else {
          gstore(C, (size_t)(rowb + i) * Ndim + col, v);
        }
      }
    }
  }
}

struct G3 {
  const ushort* A[3];
  const ushort* W[3];
  const float* bias[3];
  ushort* C[3];
  float scale[3];
};

__global__ __launch_bounds__(256) void gemm_qkv(G3 g) {
  __shared__ alignas(16) ushort a_s[128 * 32];
  __shared__ alignas(16) ushort b_s[128 * 32];
  const int z = blockIdx.z;
  gemm_core<ushort>(g.A[z], g.W[z], g.bias[z], g.C[z], g.scale[z], z == 2, a_s, b_s);
}

// ---------------------------------------------------------------------------
// O projection: 128x64 tile, BK=32.
template <typename OutT, int VT>
__global__ __launch_bounds__(256) void gemm128(const ushort* __restrict__ A,
                                               const ushort* __restrict__ W,
                                               const float* __restrict__ bias,
                                               OutT* __restrict__ C, float scale) {
  const int t = threadIdx.x;
  const int w = t >> 6, lane = t & 63;
  const int quad = lane >> 4, r16 = lane & 15;
  const int wr = w >> 1, wc = w & 1;
  const int row0 = blockIdx.x * 128, col0 = blockIdx.y * 64;

  __shared__ alignas(16) ushort a_s[128 * 32];
  __shared__ alignas(16) ushort b_s[64 * 32];

  const int sr = lane >> 2, sc = (lane & 3) * 8;
  const ushort* Ag0 = A + (size_t)(row0 + w * 32 + sr) * Kdim + sc;
  const ushort* Ag1 = Ag0 + (size_t)16 * Kdim;
  const ushort* Wg  = W + (size_t)(col0 + w * 16 + sr) * Kdim + sc;
  ushort* al0 = &a_s[(w * 32) * 32];
  ushort* al1 = &a_s[(w * 32 + 16) * 32];
  ushort* bl  = &b_s[(w * 16) * 32];

  f32x4 acc[4][2];
#pragma unroll
  for (int mt = 0; mt < 4; ++mt)
#pragma unroll
    for (int nt = 0; nt < 2; ++nt) acc[mt][nt] = (f32x4){0.f, 0.f, 0.f, 0.f};

  for (int k0 = 0; k0 < Kdim; k0 += 32) {
    __syncthreads();
    async_copy16(Ag0 + k0, al0);
    async_copy16(Ag1 + k0, al1);
    async_copy16(Wg + k0, bl);
    __syncthreads();

    bf16x8 af[4], bfr[2];
#pragma unroll
    for (int mt = 0; mt < 4; ++mt)
      af[mt] = *(const bf16x8*)&a_s[(wr * 64 + mt * 16 + r16) * 32 + quad * 8];
#pragma unroll
    for (int nt = 0; nt < 2; ++nt)
      bfr[nt] = *(const bf16x8*)&b_s[(wc * 32 + nt * 16 + r16) * 32 + quad * 8];
#pragma unroll
    for (int mt = 0; mt < 4; ++mt)
#pragma unroll
      for (int nt = 0; nt < 2; ++nt)
        acc[mt][nt] = __builtin_amdgcn_mfma_f32_16x16x32_bf16(af[mt], bfr[nt],
                                                              acc[mt][nt], 0, 0, 0);
  }

#pragma unroll
  for (int mt = 0; mt < 4; ++mt) {
#pragma unroll
    for (int nt = 0; nt < 2; ++nt) {
      const int col = col0 + wc * 32 + nt * 16 + r16;
      const float bv = bias[col];
      const int rowb = row0 + wr * 64 + mt * 16 + quad * 4;
#pragma unroll
      for (int i = 0; i < 4; ++i) {
        const float v = (acc[mt][nt][i] + bv) * scale;
        if (VT) {
          const int row = rowb + i;
          const int bb = row >> 11, ss = row & (S_ - 1);
          const int hh = col >> 6, dd = col & 63;
          gstore(C, (((size_t)bb * NH + hh) * 64 + dd) * S_ + ss, v);
        } else {
          gstore(C, (size_t)(rowb + i) * Ndim + col, v);
        }
      }
    }
  }
}

// ---------------------------------------------------------------------------
// MFMA flash attention, no-max softmax, SWAPPED QK^T (P lane-local per q-row).
// Per wave: 16 q-rows. sacc[nt][i] = S[key=16nt+4*quad+i][q=r16].
// P -> PV A-fragment built in-register: pack bf16 pairs, cross-quad shfl.
// K/V double-buffered in LDS, ONE barrier per 64-key tile. No p_s LDS.
__global__ __launch_bounds__(256) void attn_mfma(const ushort* __restrict__ Qp,
                                                 const ushort* __restrict__ Kp,
                                                 const ushort* __restrict__ Vt,
                                                 const unsigned long long* __restrict__ mb,
                                                 ushort* __restrict__ Oa) {
  const int bh = blockIdx.y;
  const int b = bh >> 4, h = bh & 15;
  const int q0 = blockIdx.x * 64;
  const int t = threadIdx.x;
  const int w = t >> 6, lane = t & 63, quad = lane >> 4, r16 = lane & 15;
  const size_t rb = (size_t)b * S_;

  // k_s:[key][dk], vt_s:[dk][key]; 8-chunks XOR-swizzled: chunk' = c ^ (row&7)
  __shared__ alignas(16) ushort k_s[2][64 * 64];
  __shared__ alignas(16) ushort vt_s[2][64 * 64];

  // Q as B-fragment: lane holds Q[q=r16][dk=quad*8+j]
  const ushort* qptr = Qp + (rb + q0 + w * 16 + r16) * DM + h * 64 + quad * 8;
  const bf16x8 aq0 = *(const bf16x8*)qptr;
  const bf16x8 aq1 = *(const bf16x8*)(qptr + 32);

  // mask words for q-row r16 (one u64 per 64-key tile)
  const unsigned long long* mrow = mb + (rb + q0 + w * 16 + r16) * (S_ >> 6);

  float l_acc = 0.f;
  f32x4 oacc[4];
#pragma unroll
  for (int nt = 0; nt < 4; ++nt) oacc[nt] = (f32x4){0.f, 0.f, 0.f, 0.f};

  // cross-quad exchange sources (loop-invariant)
  const int src0 = r16 + (((2 * quad) & 3) << 4);
  const int src1 = r16 + (((2 * quad + 1) & 3) << 4);
  const bool qlow = quad < 2;

  const int srow = t >> 3, schunk = t & 7;  // staging: 2 rounds of 32 rows
  const ushort* kbase = Kp + (rb + srow) * DM + h * 64 + schunk * 8;
  const ushort* vbase = Vt + ((size_t)bh * 64 + srow) * S_ + schunk * 8;
  const int srow2 = srow + 32;
  const int soff1 = srow * 64 + ((schunk ^ (srow & 7)) * 8);
  const int soff2 = srow2 * 64 + ((schunk ^ (srow2 & 7)) * 8);

  // prologue: tile 0 -> buf 0; prefetch tile 1 into regs
  bf16x8 kr0 = *(const bf16x8*)(kbase);
  bf16x8 kr1 = *(const bf16x8*)(kbase + (size_t)32 * DM);
  bf16x8 vr0 = *(const bf16x8*)(vbase);
  bf16x8 vr1 = *(const bf16x8*)(vbase + (size_t)32 * S_);
  *(bf16x8*)&k_s[0][soff1] = kr0;
  *(bf16x8*)&k_s[0][soff2] = kr1;
  *(bf16x8*)&vt_s[0][soff1] = vr0;
  *(bf16x8*)&vt_s[0][soff2] = vr1;
  kr0 = *(const bf16x8*)(kbase + (size_t)64 * DM);
  kr1 = *(const bf16x8*)(kbase + (size_t)96 * DM);
  vr0 = *(const bf16x8*)(vbase + 64);
  vr1 = *(const bf16x8*)(vbase + (size_t)32 * S_ + 64);

  int cur = 0;
  for (int kt = 0; kt < S_; kt += 64) {
    __syncthreads();  // buf[cur] (tile kt) writes visible; prev reads of buf[cur^1] done
    const int ktn = kt + 64;
    if (ktn < S_) {
      // stage tile kt+64 into the other buffer (others read buf[cur])
      *(bf16x8*)&k_s[cur ^ 1][soff1] = kr0;
      *(bf16x8*)&k_s[cur ^ 1][soff2] = kr1;
      *(bf16x8*)&vt_s[cur ^ 1][soff1] = vr0;
      *(bf16x8*)&vt_s[cur ^ 1][soff2] = vr1;
      const int ktnn = kt + 128;
      if (ktnn < S_) {  // prefetch tile kt+128 (latency hides under compute)
        kr0 = *(const bf16x8*)(kbase + (size_t)ktnn * DM);
        kr1 = *(const bf16x8*)(kbase + (size_t)(ktnn + 32) * DM);
        vr0 = *(const bf16x8*)(vbase + ktnn);
        vr1 = *(const bf16x8*)(vbase + (size_t)32 * S_ + ktnn);
      }
    }

    // ---- S^T = K Q^T : sacc[nt][i] = S[key=16nt+4q+i][q=r16]
    bf16x8 kf0[4], kf1[4];
#pragma unroll
    for (int nt = 0; nt < 4; ++nt) {
      const int krow = nt * 16 + r16;
      kf0[nt] = *(const bf16x8*)&k_s[cur][krow * 64 + ((quad ^ (krow & 7)) * 8)];
      kf1[nt] = *(const bf16x8*)&k_s[cur][krow * 64 + (((4 + quad) ^ (krow & 7)) * 8)];
    }
    f32x4 sacc[4];
    __builtin_amdgcn_s_setprio(1);
#pragma unroll
    for (int nt = 0; nt < 4; ++nt) {
      sacc[nt] = (f32x4){0.f, 0.f, 0.f, 0.f};
      sacc[nt] = __builtin_amdgcn_mfma_f32_16x16x32_bf16(kf0[nt], aq0, sacc[nt], 0, 0, 0);
      sacc[nt] = __builtin_amdgcn_mfma_f32_16x16x32_bf16(kf1[nt], aq1, sacc[nt], 0, 0, 0);
    }
    __builtin_amdgcn_s_setprio(0);

    // ---- mask bit + exp2; pack P pairs to bf16 dwords (lane-local q-row)
    const unsigned long long mw = mrow[kt >> 6];
    unsigned d[4][2];
#pragma unroll
    for (int nt = 0; nt < 4; ++nt) {
      const unsigned bits = (unsigned)(mw >> (nt * 16 + quad * 4));
      const float p0 = (bits & 1u) ? exp2f(sacc[nt][0]) : 0.f;
      const float p1 = (bits & 2u) ? exp2f(sacc[nt][1]) : 0.f;
      const float p2 = (bits & 4u) ? exp2f(sacc[nt][2]) : 0.f;
      const float p3 = (bits & 8u) ? exp2f(sacc[nt][3]) : 0.f;
      l_acc += (p0 + p1) + (p2 + p3);
      d[nt][0] = pack_bf16(p0, p1);
      d[nt][1] = pack_bf16(p2, p3);
    }

    // ---- cross-quad exchange -> pa keys = 32ks + 8*quad + j; then PV
#pragma unroll
    for (int ks = 0; ks < 2; ++ks) {
      const unsigned a0 = __shfl(d[2 * ks][0], src0), b0 = __shfl(d[2 * ks + 1][0], src0);
      const unsigned a1 = __shfl(d[2 * ks][1], src0), b1 = __shfl(d[2 * ks + 1][1], src0);
      const unsigned a2 = __shfl(d[2 * ks][0], src1), b2 = __shfl(d[2 * ks + 1][0], src1);
      const unsigned a3 = __shfl(d[2 * ks][1], src1), b3 = __shfl(d[2 * ks + 1][1], src1);
      union { unsigned u[4]; bf16x8 v; } pu;
      pu.u[0] = qlow ? a0 : b0;
      pu.u[1] = qlow ? a1 : b1;
      pu.u[2] = qlow ? a2 : b2;
      pu.u[3] = qlow ? a3 : b3;
      const int kc = ks * 4 + quad;
      bf16x8 vb[4];
#pragma unroll
      for (int nt = 0; nt < 4; ++nt) {
        const int dk = nt * 16 + r16;
        vb[nt] = *(const bf16x8*)&vt_s[cur][dk * 64 + ((kc ^ (dk & 7)) * 8)];
      }
      __builtin_amdgcn_s_setprio(1);
#pragma unroll
      for (int nt = 0; nt < 4; ++nt)
        oacc[nt] = __builtin_amdgcn_mfma_f32_16x16x32_bf16(pu.v, vb[nt], oacc[nt], 0, 0, 0);
      __builtin_amdgcn_s_setprio(0);
    }
    cur ^= 1;
  }

  // ---- epilogue: l for q-row r16 lives per-lane; reduce across quads,
  // then redistribute to the store layout (row = 4*quad + i)
  l_acc += __shfl_xor(l_acc, 16);
  l_acc += __shfl_xor(l_acc, 32);
  float ldiv[4];
#pragma unroll
  for (int i = 0; i < 4; ++i) ldiv[i] = __shfl(l_acc, quad * 4 + i);

#pragma unroll
  for (int nt = 0; nt < 4; ++nt) {
#pragma unroll
    for (int i = 0; i < 4; ++i) {
      const int row = q0 + w * 16 + quad * 4 + i;
      const int col = h * 64 + nt * 16 + r16;
      Oa[(rb + row) * DM + col] = (ushort)f2b(oacc[nt][i] / ldiv[i]);
    }
  }
}

// ---------------------------------------------------------------------------
// Workspace = 56 MB exactly:
//   qc,kc,vc (3*NE u16) | Qp,Kp,Vt (3*NE u16) | 4 weights (4*NW u16)
//   attn output reuses qc; mask bit-words (1 MB) reuse vc (free after V GEMM).
extern "C" void kernel_launch(void* const* d_in, const int* in_sizes, int n_in,
                              void* d_out, int out_size, void* d_ws, size_t ws_size,
                              hipStream_t stream) {
  const int* mask = (const int*)d_in[3];
  const float* bq = (const float*)d_in[5];
  const float* bk = (const float*)d_in[7];
  const float* bv = (const float*)d_in[9];
  const float* bo = (const float*)d_in[11];

  const size_t NE = (size_t)B_ * S_ * DM;  // 4M
  const size_t NW = (size_t)DM * DM;       // 1M

  ushort* qc = (ushort*)d_ws;
  ushort* kc = qc + NE;
  ushort* vc = kc + NE;
  ushort* Qp = vc + NE;
  ushort* Kp = Qp + NE;
  ushort* Vt = Kp + NE;
  ushort* Wqc = Vt + NE;
  ushort* Wkc = Wqc + NW;
  ushort* Wvc = Wkc + NW;
  ushort* Woc = Wvc + NW;
  unsigned long long* mbits = (unsigned long long*)vc;  // 131072 words = 1 MB

  Cvt7 c;
  const int sidx[7] = {0, 1, 2, 4, 6, 8, 10};
  ushort* dsts[7] = {qc, kc, vc, Wqc, Wkc, Wvc, Woc};
  for (int i = 0; i < 7; ++i) {
    c.src[i] = (const float*)d_in[sidx[i]];
    c.dst[i] = dsts[i];
    c.n[i] = (i < 3) ? (int)NE : (int)NW;
  }
  cvt_all<<<dim3(2048, 7), 256, 0, stream>>>(c);

  // Q projection pre-scaled by (1/sqrt(dk)) * log2(e) so attn uses exp2
  G3 g;
  g.A[0] = qc;  g.A[1] = kc;  g.A[2] = vc;
  g.W[0] = Wqc; g.W[1] = Wkc; g.W[2] = Wvc;
  g.bias[0] = bq; g.bias[1] = bk; g.bias[2] = bv;
  g.C[0] = Qp;  g.C[1] = Kp;  g.C[2] = Vt;
  g.scale[0] = 0.125f * 1.4426950408889634f;
  g.scale[1] = 1.0f;
  g.scale[2] = 1.0f;
  gemm_qkv<<<dim3(Mdim / 128, Ndim / 128, 3), 256, 0, stream>>>(g);

  // pack mask into vc region (V GEMM has consumed vc by now)
  mask_bits<<<(B_ * S_ * S_) / 256, 256, 0, stream>>>(mask, mbits);

  attn_mfma<<<dim3(S_ / 64, B_ * NH), 256, 0, stream>>>(Qp, Kp, Vt, mbits, qc);

  gemm128<float, 0><<<dim3(Mdim / 128, Ndim / 64), 256, 0, stream>>>(
      qc, Woc, bo, (float*)d_out, 1.0f);
}

// Round 3
// 288.595 us; speedup vs baseline: 1.0174x; 1.0174x over previous
//
#include <hip/hip_runtime.h>
#include <hip/hip_bf16.h>

#define B_   2
#define S_   2048
#define DM   1024
#define NH   16
#define DKH  64
#define Mdim 4096
#define Ndim 1024
#define Kdim 1024

typedef __attribute__((ext_vector_type(8))) short bf16x8;
typedef __attribute__((ext_vector_type(4))) short bf16x4;
typedef __attribute__((ext_vector_type(4))) float f32x4;
typedef __attribute__((ext_vector_type(16))) float f32x16;

__device__ __forceinline__ short f2b(float x) {
  union { __hip_bfloat16 h; short s; } u;
  u.h = __float2bfloat16(x);
  return u.s;
}

// async global->LDS, 16 B/lane; LDS dst = wave-uniform base + lane*16
__device__ __forceinline__ void async_copy16(const void* g, void* l) {
  __builtin_amdgcn_global_load_lds(
      (const __attribute__((address_space(1))) unsigned int*)g,
      (__attribute__((address_space(3))) unsigned int*)l, 16, 0, 0);
}

// ---------------------------------------------------------------------------
// Batched fp32 -> bf16 conversion (7 tensors, one launch).
struct Cvt7 {
  const float* src[7];
  ushort* dst[7];
  int n[7];
};

__global__ __launch_bounds__(256) void cvt_all(Cvt7 c) {
  const int ten = blockIdx.y;
  const int base = (blockIdx.x * 256 + threadIdx.x) * 8;
  if (base >= c.n[ten]) return;
  const float* s = c.src[ten] + base;
  float4 a = *(const float4*)s;
  float4 b = *(const float4*)(s + 4);
  bf16x8 r;
  r[0] = f2b(a.x); r[1] = f2b(a.y); r[2] = f2b(a.z); r[3] = f2b(a.w);
  r[4] = f2b(b.x); r[5] = f2b(b.y); r[6] = f2b(b.z); r[7] = f2b(b.w);
  *(bf16x8*)(c.dst[ten] + base) = r;
}

// ---------------------------------------------------------------------------
// Pack int32 mask -> 1 bit/key, TRANSPOSED for coalesced per-tile reads:
// mbT[kw * (B*S) + (b*S + q)], bit j = key kw*64 + j.
__global__ __launch_bounds__(256) void mask_bits(const int* __restrict__ m,
                                                 unsigned long long* __restrict__ mb) {
  const size_t i = (size_t)blockIdx.x * 256 + threadIdx.x;
  const unsigned long long bits = __ballot(m[i] != 0);
  if ((threadIdx.x & 63) == 0) {
    const size_t word = i >> 6;          // (b*S+q)*32 + kw
    const size_t kw = word & 31;
    const size_t row = word >> 5;        // b*S + q
    mb[kw * (size_t)(B_ * S_) + row] = bits;
  }
}

// ---------------------------------------------------------------------------
__device__ __forceinline__ void gstore(float* C, size_t i, float v) { C[i] = v; }
__device__ __forceinline__ void gstore(ushort* C, size_t i, float v) { C[i] = (ushort)f2b(v); }

// m97-structure core: C[4096,1024] = A@W^T + bias, *scale. 128x128 tile,
// BK=32, LDS via global_load_lds(16B). 4 waves 2x2; wave = 64x64 (4x4 frags).
// vt=1: write head-transposed [b][h][d][s] (for V).
template <typename OutT>
__device__ __forceinline__ void gemm_core(const ushort* __restrict__ A,
                                          const ushort* __restrict__ W,
                                          const float* __restrict__ bias,
                                          OutT* __restrict__ C, float scale, int vt,
                                          ushort* a_s, ushort* b_s) {
  const int t = threadIdx.x;
  const int w = t >> 6, lane = t & 63;
  const int quad = lane >> 4, r16 = lane & 15;
  const int wr = w >> 1, wc = w & 1;
  const int row0 = blockIdx.x * 128, col0 = blockIdx.y * 128;

  const int sr = t >> 2, sc = (t & 3) * 8;
  const ushort* Ag0 = A + (size_t)(row0 + sr) * Kdim + sc;
  const ushort* Ag1 = Ag0 + (size_t)64 * Kdim;
  const ushort* Wg0 = W + (size_t)(col0 + sr) * Kdim + sc;
  const ushort* Wg1 = Wg0 + (size_t)64 * Kdim;
  ushort* al0 = a_s + (w * 16) * 32;
  ushort* al1 = a_s + (64 + w * 16) * 32;
  ushort* bl0 = b_s + (w * 16) * 32;
  ushort* bl1 = b_s + (64 + w * 16) * 32;

  f32x4 acc[4][4];
#pragma unroll
  for (int mt = 0; mt < 4; ++mt)
#pragma unroll
    for (int nt = 0; nt < 4; ++nt) acc[mt][nt] = (f32x4){0.f, 0.f, 0.f, 0.f};

  for (int k0 = 0; k0 < Kdim; k0 += 32) {
    __syncthreads();
    async_copy16(Ag0 + k0, al0);
    async_copy16(Ag1 + k0, al1);
    async_copy16(Wg0 + k0, bl0);
    async_copy16(Wg1 + k0, bl1);
    __syncthreads();

    bf16x8 af[4], bfr[4];
#pragma unroll
    for (int mt = 0; mt < 4; ++mt)
      af[mt] = *(const bf16x8*)&a_s[(wr * 64 + mt * 16 + r16) * 32 + quad * 8];
#pragma unroll
    for (int nt = 0; nt < 4; ++nt)
      bfr[nt] = *(const bf16x8*)&b_s[(wc * 64 + nt * 16 + r16) * 32 + quad * 8];
#pragma unroll
    for (int mt = 0; mt < 4; ++mt)
#pragma unroll
      for (int nt = 0; nt < 4; ++nt)
        acc[mt][nt] = __builtin_amdgcn_mfma_f32_16x16x32_bf16(af[mt], bfr[nt],
                                                              acc[mt][nt], 0, 0, 0);
  }

#pragma unroll
  for (int mt = 0; mt < 4; ++mt) {
#pragma unroll
    for (int nt = 0; nt < 4; ++nt) {
      const int col = col0 + wc * 64 + nt * 16 + r16;
      const float bv = bias[col];
      const int rowb = row0 + wr * 64 + mt * 16 + quad * 4;
#pragma unroll
      for (int i = 0; i < 4; ++i) {
        const float v = (acc[mt][nt][i] + bv) * scale;
        if (vt) {
          const int row = rowb + i;
          const int bb = row >> 11, ss = row & (S_ - 1);   // row = b*S + s
          const int hh = col >> 6, dd = col & 63;          // col = h*64 + d
          gstore(C, (((size_t)bb * NH + hh) * 64 + dd) * S_ + ss, v);
        } else {
          gstore(C, (size_t)(rowb + i) * Ndim + col, v);
        }
      }
    }
  }
}

struct G3 {
  const ushort* A[3];
  const ushort* W[3];
  const float* bias[3];
  ushort* C[3];
  float scale[3];
};

__global__ __launch_bounds__(256) void gemm_qkv(G3 g) {
  __shared__ alignas(16) ushort a_s[128 * 32];
  __shared__ alignas(16) ushort b_s[128 * 32];
  const int z = blockIdx.z;
  gemm_core<ushort>(g.A[z], g.W[z], g.bias[z], g.C[z], g.scale[z], z == 2, a_s, b_s);
}

// ---------------------------------------------------------------------------
// O projection: 128x64 tile, BK=32.
template <typename OutT, int VT>
__global__ __launch_bounds__(256) void gemm128(const ushort* __restrict__ A,
                                               const ushort* __restrict__ W,
                                               const float* __restrict__ bias,
                                               OutT* __restrict__ C, float scale) {
  const int t = threadIdx.x;
  const int w = t >> 6, lane = t & 63;
  const int quad = lane >> 4, r16 = lane & 15;
  const int wr = w >> 1, wc = w & 1;
  const int row0 = blockIdx.x * 128, col0 = blockIdx.y * 64;

  __shared__ alignas(16) ushort a_s[128 * 32];
  __shared__ alignas(16) ushort b_s[64 * 32];

  const int sr = lane >> 2, sc = (lane & 3) * 8;
  const ushort* Ag0 = A + (size_t)(row0 + w * 32 + sr) * Kdim + sc;
  const ushort* Ag1 = Ag0 + (size_t)16 * Kdim;
  const ushort* Wg  = W + (size_t)(col0 + w * 16 + sr) * Kdim + sc;
  ushort* al0 = &a_s[(w * 32) * 32];
  ushort* al1 = &a_s[(w * 32 + 16) * 32];
  ushort* bl  = &b_s[(w * 16) * 32];

  f32x4 acc[4][2];
#pragma unroll
  for (int mt = 0; mt < 4; ++mt)
#pragma unroll
    for (int nt = 0; nt < 2; ++nt) acc[mt][nt] = (f32x4){0.f, 0.f, 0.f, 0.f};

  for (int k0 = 0; k0 < Kdim; k0 += 32) {
    __syncthreads();
    async_copy16(Ag0 + k0, al0);
    async_copy16(Ag1 + k0, al1);
    async_copy16(Wg + k0, bl);
    __syncthreads();

    bf16x8 af[4], bfr[2];
#pragma unroll
    for (int mt = 0; mt < 4; ++mt)
      af[mt] = *(const bf16x8*)&a_s[(wr * 64 + mt * 16 + r16) * 32 + quad * 8];
#pragma unroll
    for (int nt = 0; nt < 2; ++nt)
      bfr[nt] = *(const bf16x8*)&b_s[(wc * 32 + nt * 16 + r16) * 32 + quad * 8];
#pragma unroll
    for (int mt = 0; mt < 4; ++mt)
#pragma unroll
      for (int nt = 0; nt < 2; ++nt)
        acc[mt][nt] = __builtin_amdgcn_mfma_f32_16x16x32_bf16(af[mt], bfr[nt],
                                                              acc[mt][nt], 0, 0, 0);
  }

#pragma unroll
  for (int mt = 0; mt < 4; ++mt) {
#pragma unroll
    for (int nt = 0; nt < 2; ++nt) {
      const int col = col0 + wc * 32 + nt * 16 + r16;
      const float bv = bias[col];
      const int rowb = row0 + wr * 64 + mt * 16 + quad * 4;
#pragma unroll
      for (int i = 0; i < 4; ++i) {
        const float v = (acc[mt][nt][i] + bv) * scale;
        if (VT) {
          const int row = rowb + i;
          const int bb = row >> 11, ss = row & (S_ - 1);
          const int hh = col >> 6, dd = col & 63;
          gstore(C, (((size_t)bb * NH + hh) * 64 + dd) * S_ + ss, v);
        } else {
          gstore(C, (size_t)(rowb + i) * Ndim + col, v);
        }
      }
    }
  }
}

// ---------------------------------------------------------------------------
// MFMA flash attention, 32x32x16 shape, swapped QK^T, permlane exchange.
// 4 waves x 32 q-rows = 128 q-rows/block. KVBLK=64, double-buffered LDS
// staged via global_load_lds with pre-swizzled global source (m173).
// A-frag (32x32x16): m=lane&31, k=8*(lane>>5)+j. B-frag: n=lane&31, same k.
// C/D: col=lane&31, row=(reg&3)+8*(reg>>2)+4*(lane>>5).
__global__ __launch_bounds__(256, 2) void attn_mfma(const ushort* __restrict__ Qp,
                                                    const ushort* __restrict__ Kp,
                                                    const ushort* __restrict__ Vt,
                                                    const unsigned long long* __restrict__ mbT,
                                                    ushort* __restrict__ Oa) {
  const int bh = blockIdx.y;
  const int b = bh >> 4, h = bh & 15;
  const int q0 = blockIdx.x * 128;
  const int t = threadIdx.x;
  const int w = t >> 6, lane = t & 63;
  const int l31 = lane & 31, hi = lane >> 5, l7 = lane & 7;
  const size_t rb = (size_t)b * S_;

  // [row][chunk] with 8-elem (16B) chunks XOR-swizzled: slot = c ^ (row&7)
  __shared__ alignas(16) ushort k_s[2][64 * 64];   // [key][dk]
  __shared__ alignas(16) ushort vt_s[2][64 * 64];  // [dk][key]

  // Q B-frags: qf[s] holds Q[qrow][dk = 16s + 8hi + j]
  const int qrow = q0 + w * 32 + l31;
  const ushort* qp = Qp + (rb + qrow) * DM + h * 64 + hi * 8;
  bf16x8 qf[4];
#pragma unroll
  for (int s = 0; s < 4; ++s) qf[s] = *(const bf16x8*)(qp + 16 * s);

  // staging: lane l -> LDS row base+(l>>3), slot l&7; global chunk pre-swizzled
  const int srow = lane >> 3;
  const int schk = l7 ^ srow;
  const int kr0 = w * 16 + srow;
  const ushort* kg0 = Kp + (rb + kr0) * DM + h * 64 + schk * 8;
  const ushort* kg1 = kg0 + (size_t)8 * DM;
  const ushort* vg0 = Vt + ((size_t)bh * 64 + kr0) * S_ + schk * 8;
  const ushort* vg1 = vg0 + (size_t)8 * S_;
  const int lo0 = (w * 16) * 64;
  const int lo1 = (w * 16 + 8) * 64;

  // swizzled read offsets for chunk c = 2x + hi (reader row&7 == l31&7 == l7)
  int off[4];
#pragma unroll
  for (int x = 0; x < 4; ++x) off[x] = ((2 * x + hi) ^ l7) * 8;

  f32x16 oacc[2];
#pragma unroll
  for (int i = 0; i < 16; ++i) { oacc[0][i] = 0.f; oacc[1][i] = 0.f; }
  float l_acc = 0.f;

  // prologue: stage tile 0 -> buf 0
  async_copy16(kg0, &k_s[0][lo0]);
  async_copy16(kg1, &k_s[0][lo1]);
  async_copy16(vg0, &vt_s[0][lo0]);
  async_copy16(vg1, &vt_s[0][lo1]);
  __syncthreads();

  const unsigned long long* mcol = mbT + (rb + qrow);

  int cur = 0;
  for (int kt = 0; kt < S_; kt += 64) {
    const int nxt = cur ^ 1;
    // issue next tile's stage first; latency hides under this tile's compute
    if (kt + 64 < S_) {
      async_copy16(kg0 + (size_t)(kt + 64) * DM, &k_s[nxt][lo0]);
      async_copy16(kg1 + (size_t)(kt + 64) * DM, &k_s[nxt][lo1]);
      async_copy16(vg0 + (kt + 64), &vt_s[nxt][lo0]);
      async_copy16(vg1 + (kt + 64), &vt_s[nxt][lo1]);
    }
    const unsigned long long mw = mcol[(size_t)(kt >> 6) * (B_ * S_)];

    // ---- S^T = K Q^T : sacc[g] = S^T[key=32g+(reg&3)+8(reg>>2)+4hi][q=l31]
    bf16x8 kf[2][4];
#pragma unroll
    for (int g = 0; g < 2; ++g)
#pragma unroll
      for (int s = 0; s < 4; ++s)
        kf[g][s] = *(const bf16x8*)&k_s[cur][(32 * g + l31) * 64 + off[s]];

    f32x16 sacc[2];
#pragma unroll
    for (int i = 0; i < 16; ++i) { sacc[0][i] = 0.f; sacc[1][i] = 0.f; }
    __builtin_amdgcn_s_setprio(1);
#pragma unroll
    for (int g = 0; g < 2; ++g)
#pragma unroll
      for (int s = 0; s < 4; ++s)
        sacc[g] = __builtin_amdgcn_mfma_f32_32x32x16_bf16(kf[g][s], qf[s], sacc[g], 0, 0, 0);
    __builtin_amdgcn_s_setprio(0);

    // ---- mask bit -> {0,1} float, exp2 (Q carries log2e), pack to bf16 pairs
    const unsigned long long ms = mw >> (4 * hi);
    unsigned pd[2][8];
#pragma unroll
    for (int g = 0; g < 2; ++g) {
      const unsigned mword = (unsigned)(ms >> (32 * g));
      float p[16];
#pragma unroll
      for (int reg = 0; reg < 16; ++reg) {
        const int base = (reg & 3) + 8 * (reg >> 2);
        const float bitf = (float)((mword >> base) & 1u);
        p[reg] = exp2f(sacc[g][reg]) * bitf;
      }
#pragma unroll
      for (int reg = 0; reg < 16; ++reg) l_acc += p[reg];
#pragma unroll
      for (int r = 0; r < 8; ++r) {
        unsigned dst;
        asm("v_cvt_pk_bf16_f32 %0, %1, %2" : "=v"(dst) : "v"(p[2 * r]), "v"(p[2 * r + 1]));
        pd[g][r] = dst;
      }
    }

    // ---- permlane exchange -> PV A-frags; O += P V
    // slice tt keys [16tt,16tt+16): swap(pd[g][4tp], pd[g][4tp+2]) -> m0,m2;
    // swap(pd[g][4tp+1], pd[g][4tp+3]) -> m1,m3.  (g=tt>>1, tp=tt&1)
#pragma unroll
    for (int tt = 0; tt < 4; ++tt) {
      const int g = tt >> 1, tp = tt & 1;
      unsigned x0 = pd[g][4 * tp + 0], x2 = pd[g][4 * tp + 2];
      unsigned x1 = pd[g][4 * tp + 1], x3 = pd[g][4 * tp + 3];
      asm("v_permlane32_swap_b32 %0, %1" : "+v"(x0), "+v"(x2));
      asm("v_permlane32_swap_b32 %0, %1" : "+v"(x1), "+v"(x3));
      union { unsigned u[4]; bf16x8 v; } pa;
      pa.u[0] = x0; pa.u[1] = x1; pa.u[2] = x2; pa.u[3] = x3;
      bf16x8 vb0 = *(const bf16x8*)&vt_s[cur][l31 * 64 + off[tt]];
      bf16x8 vb1 = *(const bf16x8*)&vt_s[cur][(32 + l31) * 64 + off[tt]];
      __builtin_amdgcn_s_setprio(1);
      oacc[0] = __builtin_amdgcn_mfma_f32_32x32x16_bf16(pa.v, vb0, oacc[0], 0, 0, 0);
      oacc[1] = __builtin_amdgcn_mfma_f32_32x32x16_bf16(pa.v, vb1, oacc[1], 0, 0, 0);
      __builtin_amdgcn_s_setprio(0);
    }
    __syncthreads();
    cur = nxt;
  }

  // ---- epilogue: l per q-row (lane & lane+32 halves), divide, store
  l_acc += __shfl_xor(l_acc, 32);
  const float linv = 1.0f / l_acc;  // lane l31 holds inv-l for q-row l31
#pragma unroll
  for (int reg = 0; reg < 16; ++reg) {
    const int base = (reg & 3) + 8 * (reg >> 2);
    const float li = __shfl(linv, base + 4 * hi);
    const int qa = q0 + w * 32 + base + 4 * hi;
    const size_t ro = (rb + qa) * DM + h * 64 + l31;
    Oa[ro] = (ushort)f2b(oacc[0][reg] * li);
    Oa[ro + 32] = (ushort)f2b(oacc[1][reg] * li);
  }
}

// ---------------------------------------------------------------------------
// Workspace = 56 MB exactly:
//   qc,kc,vc (3*NE u16) | Qp,Kp,Vt (3*NE u16) | 4 weights (4*NW u16)
//   attn output reuses qc; mask bit-words (1 MB) reuse vc (free after V GEMM).
extern "C" void kernel_launch(void* const* d_in, const int* in_sizes, int n_in,
                              void* d_out, int out_size, void* d_ws, size_t ws_size,
                              hipStream_t stream) {
  const int* mask = (const int*)d_in[3];
  const float* bq = (const float*)d_in[5];
  const float* bk = (const float*)d_in[7];
  const float* bv = (const float*)d_in[9];
  const float* bo = (const float*)d_in[11];

  const size_t NE = (size_t)B_ * S_ * DM;  // 4M
  const size_t NW = (size_t)DM * DM;       // 1M

  ushort* qc = (ushort*)d_ws;
  ushort* kc = qc + NE;
  ushort* vc = kc + NE;
  ushort* Qp = vc + NE;
  ushort* Kp = Qp + NE;
  ushort* Vt = Kp + NE;
  ushort* Wqc = Vt + NE;
  ushort* Wkc = Wqc + NW;
  ushort* Wvc = Wkc + NW;
  ushort* Woc = Wvc + NW;
  unsigned long long* mbits = (unsigned long long*)vc;  // 131072 words = 1 MB

  Cvt7 c;
  const int sidx[7] = {0, 1, 2, 4, 6, 8, 10};
  ushort* dsts[7] = {qc, kc, vc, Wqc, Wkc, Wvc, Woc};
  for (int i = 0; i < 7; ++i) {
    c.src[i] = (const float*)d_in[sidx[i]];
    c.dst[i] = dsts[i];
    c.n[i] = (i < 3) ? (int)NE : (int)NW;
  }
  cvt_all<<<dim3(2048, 7), 256, 0, stream>>>(c);

  // Q projection pre-scaled by (1/sqrt(dk)) * log2(e) so attn uses exp2
  G3 g;
  g.A[0] = qc;  g.A[1] = kc;  g.A[2] = vc;
  g.W[0] = Wqc; g.W[1] = Wkc; g.W[2] = Wvc;
  g.bias[0] = bq; g.bias[1] = bk; g.bias[2] = bv;
  g.C[0] = Qp;  g.C[1] = Kp;  g.C[2] = Vt;
  g.scale[0] = 0.125f * 1.4426950408889634f;
  g.scale[1] = 1.0f;
  g.scale[2] = 1.0f;
  gemm_qkv<<<dim3(Mdim / 128, Ndim / 128, 3), 256, 0, stream>>>(g);

  // pack mask into vc region (V GEMM has consumed vc by now)
  mask_bits<<<(B_ * S_ * S_) / 256, 256, 0, stream>>>(mask, mbits);

  attn_mfma<<<dim3(S_ / 128, B_ * NH), 256, 0, stream>>>(Qp, Kp, Vt, mbits, qc);

  gemm128<float, 0><<<dim3(Mdim / 128, Ndim / 64), 256, 0, stream>>>(
      qc, Woc, bo, (float*)d_out, 1.0f);
}

// Round 4
// 269.913 us; speedup vs baseline: 1.0878x; 1.0692x over previous
//
#include <hip/hip_runtime.h>
#include <hip/hip_bf16.h>

#define B_   2
#define S_   2048
#define DM   1024
#define NH   16
#define DKH  64
#define Mdim 4096
#define Ndim 1024
#define Kdim 1024

typedef __attribute__((ext_vector_type(8))) short bf16x8;
typedef __attribute__((ext_vector_type(4))) short bf16x4;
typedef __attribute__((ext_vector_type(4))) float f32x4;
typedef __attribute__((ext_vector_type(16))) float f32x16;

__device__ __forceinline__ short f2b(float x) {
  union { __hip_bfloat16 h; short s; } u;
  u.h = __float2bfloat16(x);
  return u.s;
}

// async global->LDS, 16 B/lane; LDS dst = wave-uniform base + lane*16
__device__ __forceinline__ void async_copy16(const void* g, void* l) {
  __builtin_amdgcn_global_load_lds(
      (const __attribute__((address_space(1))) unsigned int*)g,
      (__attribute__((address_space(3))) unsigned int*)l, 16, 0, 0);
}
// async global->LDS, 4 B/lane; LDS dst = wave-uniform base + lane*4
__device__ __forceinline__ void async_copy4(const void* g, void* l) {
  __builtin_amdgcn_global_load_lds(
      (const __attribute__((address_space(1))) unsigned int*)g,
      (__attribute__((address_space(3))) unsigned int*)l, 4, 0, 0);
}

// ---------------------------------------------------------------------------
// Batched fp32 -> bf16 conversion (7 tensors, one launch).
struct Cvt7 {
  const float* src[7];
  ushort* dst[7];
  int n[7];
};

__global__ __launch_bounds__(256) void cvt_all(Cvt7 c) {
  const int ten = blockIdx.y;
  const int base = (blockIdx.x * 256 + threadIdx.x) * 8;
  if (base >= c.n[ten]) return;
  const float* s = c.src[ten] + base;
  float4 a = *(const float4*)s;
  float4 b = *(const float4*)(s + 4);
  bf16x8 r;
  r[0] = f2b(a.x); r[1] = f2b(a.y); r[2] = f2b(a.z); r[3] = f2b(a.w);
  r[4] = f2b(b.x); r[5] = f2b(b.y); r[6] = f2b(b.z); r[7] = f2b(b.w);
  *(bf16x8*)(c.dst[ten] + base) = r;
}

// ---------------------------------------------------------------------------
// Pack int32 mask -> 1 bit/key, TRANSPOSED for coalesced per-tile reads:
// mbT[kw * (B*S) + (b*S + q)], bit j = key kw*64 + j.
__global__ __launch_bounds__(256) void mask_bits(const int* __restrict__ m,
                                                 unsigned long long* __restrict__ mb) {
  const size_t i = (size_t)blockIdx.x * 256 + threadIdx.x;
  const unsigned long long bits = __ballot(m[i] != 0);
  if ((threadIdx.x & 63) == 0) {
    const size_t word = i >> 6;          // (b*S+q)*32 + kw
    const size_t kw = word & 31;
    const size_t row = word >> 5;        // b*S + q
    mb[kw * (size_t)(B_ * S_) + row] = bits;
  }
}

// ---------------------------------------------------------------------------
__device__ __forceinline__ void gstore(float* C, size_t i, float v) { C[i] = v; }
__device__ __forceinline__ void gstore(ushort* C, size_t i, float v) { C[i] = (ushort)f2b(v); }

// m97-structure core: C[4096,1024] = A@W^T + bias, *scale. 128x128 tile,
// BK=32, LDS via global_load_lds(16B). 4 waves 2x2; wave = 64x64 (4x4 frags).
// vt=1: write head-transposed [b][h][d][s] (for V).
template <typename OutT>
__device__ __forceinline__ void gemm_core(const ushort* __restrict__ A,
                                          const ushort* __restrict__ W,
                                          const float* __restrict__ bias,
                                          OutT* __restrict__ C, float scale, int vt,
                                          ushort* a_s, ushort* b_s) {
  const int t = threadIdx.x;
  const int w = t >> 6, lane = t & 63;
  const int quad = lane >> 4, r16 = lane & 15;
  const int wr = w >> 1, wc = w & 1;
  const int row0 = blockIdx.x * 128, col0 = blockIdx.y * 128;

  const int sr = t >> 2, sc = (t & 3) * 8;
  const ushort* Ag0 = A + (size_t)(row0 + sr) * Kdim + sc;
  const ushort* Ag1 = Ag0 + (size_t)64 * Kdim;
  const ushort* Wg0 = W + (size_t)(col0 + sr) * Kdim + sc;
  const ushort* Wg1 = Wg0 + (size_t)64 * Kdim;
  ushort* al0 = a_s + (w * 16) * 32;
  ushort* al1 = a_s + (64 + w * 16) * 32;
  ushort* bl0 = b_s + (w * 16) * 32;
  ushort* bl1 = b_s + (64 + w * 16) * 32;

  f32x4 acc[4][4];
#pragma unroll
  for (int mt = 0; mt < 4; ++mt)
#pragma unroll
    for (int nt = 0; nt < 4; ++nt) acc[mt][nt] = (f32x4){0.f, 0.f, 0.f, 0.f};

  for (int k0 = 0; k0 < Kdim; k0 += 32) {
    __syncthreads();
    async_copy16(Ag0 + k0, al0);
    async_copy16(Ag1 + k0, al1);
    async_copy16(Wg0 + k0, bl0);
    async_copy16(Wg1 + k0, bl1);
    __syncthreads();

    bf16x8 af[4], bfr[4];
#pragma unroll
    for (int mt = 0; mt < 4; ++mt)
      af[mt] = *(const bf16x8*)&a_s[(wr * 64 + mt * 16 + r16) * 32 + quad * 8];
#pragma unroll
    for (int nt = 0; nt < 4; ++nt)
      bfr[nt] = *(const bf16x8*)&b_s[(wc * 64 + nt * 16 + r16) * 32 + quad * 8];
#pragma unroll
    for (int mt = 0; mt < 4; ++mt)
#pragma unroll
      for (int nt = 0; nt < 4; ++nt)
        acc[mt][nt] = __builtin_amdgcn_mfma_f32_16x16x32_bf16(af[mt], bfr[nt],
                                                              acc[mt][nt], 0, 0, 0);
  }

#pragma unroll
  for (int mt = 0; mt < 4; ++mt) {
#pragma unroll
    for (int nt = 0; nt < 4; ++nt) {
      const int col = col0 + wc * 64 + nt * 16 + r16;
      const float bv = bias[col];
      const int rowb = row0 + wr * 64 + mt * 16 + quad * 4;
#pragma unroll
      for (int i = 0; i < 4; ++i) {
        const float v = (acc[mt][nt][i] + bv) * scale;
        if (vt) {
          const int row = rowb + i;
          const int bb = row >> 11, ss = row & (S_ - 1);   // row = b*S + s
          const int hh = col >> 6, dd = col & 63;          // col = h*64 + d
          gstore(C, (((size_t)bb * NH + hh) * 64 + dd) * S_ + ss, v);
        } else {
          gstore(C, (size_t)(rowb + i) * Ndim + col, v);
        }
      }
    }
  }
}

struct G3 {
  const ushort* A[3];
  const ushort* W[3];
  const float* bias[3];
  ushort* C[3];
  float scale[3];
};

__global__ __launch_bounds__(256) void gemm_qkv(G3 g) {
  __shared__ alignas(16) ushort a_s[128 * 32];
  __shared__ alignas(16) ushort b_s[128 * 32];
  const int z = blockIdx.z;
  gemm_core<ushort>(g.A[z], g.W[z], g.bias[z], g.C[z], g.scale[z], z == 2, a_s, b_s);
}

// ---------------------------------------------------------------------------
// O projection: 128x64 tile, BK=32.
template <typename OutT, int VT>
__global__ __launch_bounds__(256) void gemm128(const ushort* __restrict__ A,
                                               const ushort* __restrict__ W,
                                               const float* __restrict__ bias,
                                               OutT* __restrict__ C, float scale) {
  const int t = threadIdx.x;
  const int w = t >> 6, lane = t & 63;
  const int quad = lane >> 4, r16 = lane & 15;
  const int wr = w >> 1, wc = w & 1;
  const int row0 = blockIdx.x * 128, col0 = blockIdx.y * 64;

  __shared__ alignas(16) ushort a_s[128 * 32];
  __shared__ alignas(16) ushort b_s[64 * 32];

  const int sr = lane >> 2, sc = (lane & 3) * 8;
  const ushort* Ag0 = A + (size_t)(row0 + w * 32 + sr) * Kdim + sc;
  const ushort* Ag1 = Ag0 + (size_t)16 * Kdim;
  const ushort* Wg  = W + (size_t)(col0 + w * 16 + sr) * Kdim + sc;
  ushort* al0 = &a_s[(w * 32) * 32];
  ushort* al1 = &a_s[(w * 32 + 16) * 32];
  ushort* bl  = &b_s[(w * 16) * 32];

  f32x4 acc[4][2];
#pragma unroll
  for (int mt = 0; mt < 4; ++mt)
#pragma unroll
    for (int nt = 0; nt < 2; ++nt) acc[mt][nt] = (f32x4){0.f, 0.f, 0.f, 0.f};

  for (int k0 = 0; k0 < Kdim; k0 += 32) {
    __syncthreads();
    async_copy16(Ag0 + k0, al0);
    async_copy16(Ag1 + k0, al1);
    async_copy16(Wg + k0, bl);
    __syncthreads();

    bf16x8 af[4], bfr[2];
#pragma unroll
    for (int mt = 0; mt < 4; ++mt)
      af[mt] = *(const bf16x8*)&a_s[(wr * 64 + mt * 16 + r16) * 32 + quad * 8];
#pragma unroll
    for (int nt = 0; nt < 2; ++nt)
      bfr[nt] = *(const bf16x8*)&b_s[(wc * 32 + nt * 16 + r16) * 32 + quad * 8];
#pragma unroll
    for (int mt = 0; mt < 4; ++mt)
#pragma unroll
      for (int nt = 0; nt < 2; ++nt)
        acc[mt][nt] = __builtin_amdgcn_mfma_f32_16x16x32_bf16(af[mt], bfr[nt],
                                                              acc[mt][nt], 0, 0, 0);
  }

#pragma unroll
  for (int mt = 0; mt < 4; ++mt) {
#pragma unroll
    for (int nt = 0; nt < 2; ++nt) {
      const int col = col0 + wc * 32 + nt * 16 + r16;
      const float bv = bias[col];
      const int rowb = row0 + wr * 64 + mt * 16 + quad * 4;
#pragma unroll
      for (int i = 0; i < 4; ++i) {
        const float v = (acc[mt][nt][i] + bv) * scale;
        if (VT) {
          const int row = rowb + i;
          const int bb = row >> 11, ss = row & (S_ - 1);
          const int hh = col >> 6, dd = col & 63;
          gstore(C, (((size_t)bb * NH + hh) * 64 + dd) * S_ + ss, v);
        } else {
          gstore(C, (size_t)(rowb + i) * Ndim + col, v);
        }
      }
    }
  }
}

// ---------------------------------------------------------------------------
// MFMA flash attention, 32x32x16, swapped QK^T, permlane exchange.
// T3/T4: triple-buffered K/V+mask staged via global_load_lds; counted vmcnt
// (10/5/0) across RAW s_barriers — loads stay in flight 2 tiles ahead,
// never drained to 0 in the main loop. Mask applied as additive bias folded
// into the QK^T accumulator init (keep?0:-200), exp2 via raw v_exp_f32.
__global__ __launch_bounds__(256, 2) void attn_mfma(const ushort* __restrict__ Qp,
                                                    const ushort* __restrict__ Kp,
                                                    const ushort* __restrict__ Vt,
                                                    const unsigned long long* __restrict__ mbT,
                                                    ushort* __restrict__ Oa) {
  const int bh = blockIdx.y;
  const int b = bh >> 4, h = bh & 15;
  const int q0 = blockIdx.x * 128;
  const int t = threadIdx.x;
  const int w = t >> 6, lane = t & 63;
  const int l31 = lane & 31, hi = lane >> 5, l7 = lane & 7;
  const size_t rbq = (size_t)b * S_;

  // [row][chunk] with 8-elem (16B) chunks XOR-swizzled: slot = c ^ (row&7)
  __shared__ alignas(16) ushort k_s[3][64 * 64];   // [key][dk]
  __shared__ alignas(16) ushort vt_s[3][64 * 64];  // [dk][key]
  __shared__ alignas(8) unsigned long long mask_lds[3][128];

  // Q B-frags: qf[s] holds Q[qrow][dk = 16s + 8hi + j]
  const int qrow = q0 + w * 32 + l31;
  const ushort* qp = Qp + (rbq + qrow) * DM + h * 64 + hi * 8;
  bf16x8 qf[4];
#pragma unroll
  for (int s = 0; s < 4; ++s) qf[s] = *(const bf16x8*)(qp + 16 * s);

  // staging: lane l -> LDS row base+(l>>3), slot l&7; global chunk pre-swizzled
  const int srow = lane >> 3;
  const int schk = l7 ^ srow;
  const int kr0 = w * 16 + srow;
  const ushort* kg0 = Kp + (rbq + kr0) * DM + h * 64 + schk * 8;
  const ushort* kg1 = kg0 + (size_t)8 * DM;
  const ushort* vg0 = Vt + ((size_t)bh * 64 + kr0) * S_ + schk * 8;
  const ushort* vg1 = vg0 + (size_t)8 * S_;
  const int lo0 = (w * 16) * 64;
  const int lo1 = (w * 16 + 8) * 64;
  // mask words: 1 KB per tile (128 q-rows x 8B); thread t loads u32 slot t
  const uint* mgsrc = (const uint*)mbT + ((size_t)b * S_ + q0) * 2 + t;

  auto stage = [&](int buf, int ktg) {
    async_copy16(kg0 + (size_t)ktg * DM, &k_s[buf][lo0]);
    async_copy16(kg1 + (size_t)ktg * DM, &k_s[buf][lo1]);
    async_copy16(vg0 + ktg, &vt_s[buf][lo0]);
    async_copy16(vg1 + ktg, &vt_s[buf][lo1]);
    async_copy4(mgsrc + (size_t)(ktg >> 6) * (2 * B_ * S_),
                (char*)&mask_lds[0][0] + buf * 1024 + w * 256);
  };

  // swizzled read offsets for chunk c = 2x + hi (reader row&7 == l7)
  int off[4];
#pragma unroll
  for (int x = 0; x < 4; ++x) off[x] = ((2 * x + hi) ^ l7) * 8;

  f32x16 oacc[2];
#pragma unroll
  for (int i = 0; i < 16; ++i) { oacc[0][i] = 0.f; oacc[1][i] = 0.f; }
  float la[4] = {0.f, 0.f, 0.f, 0.f};

  // prologue: stage tiles 0,1 into bufs 0,1 (10 VMEM ops in flight)
  stage(0, 0);
  stage(1, 64);

  int rb3 = 0, wb3 = 2;
  for (int kt = 0; kt < S_; kt += 64) {
    // issue tile kt+128 into the 3rd buffer (readers of it finished at the
    // end-of-iter barrier two iterations ago)
    if (kt + 128 < S_) stage(wb3, kt + 128);

    // counted wait: tile kt's 5 ops (+mask) done; newer 10 stay in flight
    if (kt + 128 < S_) {
      asm volatile("s_waitcnt vmcnt(10)" ::: "memory");
    } else if (kt + 64 < S_) {
      asm volatile("s_waitcnt vmcnt(5)" ::: "memory");
    } else {
      asm volatile("s_waitcnt vmcnt(0)" ::: "memory");
    }
    __builtin_amdgcn_s_barrier();  // all waves' tile-kt writes visible

    // mask word for this lane's q-row, keys [kt, kt+64)
    const unsigned long long mw = mask_lds[rb3][w * 32 + l31];
    const unsigned long long msh = mw >> (4 * hi);
    unsigned inv[2];
    inv[0] = ~(unsigned)msh;
    inv[1] = ~(unsigned)(msh >> 32);

    // ---- S^T = K Q^T with mask bias folded into C-init:
    // sacc[g][reg] = (keep ? 0 : -200); key = 32g + (reg&3)+8*(reg>>2)+4hi
    bf16x8 kf[2][4];
#pragma unroll
    for (int g = 0; g < 2; ++g)
#pragma unroll
      for (int s = 0; s < 4; ++s)
        kf[g][s] = *(const bf16x8*)&k_s[rb3][(32 * g + l31) * 64 + off[s]];

    f32x16 sacc[2];
#pragma unroll
    for (int g = 0; g < 2; ++g)
#pragma unroll
      for (int reg = 0; reg < 16; ++reg) {
        const int base = (reg & 3) + 8 * (reg >> 2);
        const int sm = ((int)(inv[g] << (31 - base))) >> 31;  // keep?0:-1
        sacc[g][reg] = __int_as_float(sm & 0xC3480000);       // 0 or -200.0f
      }

    __builtin_amdgcn_s_setprio(1);
#pragma unroll
    for (int g = 0; g < 2; ++g)
#pragma unroll
      for (int s = 0; s < 4; ++s)
        sacc[g] = __builtin_amdgcn_mfma_f32_32x32x16_bf16(kf[g][s], qf[s], sacc[g], 0, 0, 0);
    __builtin_amdgcn_s_setprio(0);

    // ---- exp2 (Q carries log2e; masked keys = exp2(s-200) -> 0), pack pairs
    unsigned pd[2][8];
#pragma unroll
    for (int g = 0; g < 2; ++g) {
      float p[16];
#pragma unroll
      for (int reg = 0; reg < 16; ++reg) {
        float e;
        asm("v_exp_f32 %0, %1" : "=v"(e) : "v"(sacc[g][reg]));
        p[reg] = e;
      }
#pragma unroll
      for (int reg = 0; reg < 16; ++reg) la[reg & 3] += p[reg];
#pragma unroll
      for (int r = 0; r < 8; ++r) {
        unsigned dst;
        asm("v_cvt_pk_bf16_f32 %0, %1, %2" : "=v"(dst) : "v"(p[2 * r]), "v"(p[2 * r + 1]));
        pd[g][r] = dst;
      }
    }

    // ---- permlane exchange -> PV A-frags; O += P V
#pragma unroll
    for (int tt = 0; tt < 4; ++tt) {
      const int g = tt >> 1, tp = tt & 1;
      unsigned x0 = pd[g][4 * tp + 0], x2 = pd[g][4 * tp + 2];
      unsigned x1 = pd[g][4 * tp + 1], x3 = pd[g][4 * tp + 3];
      asm("v_permlane32_swap_b32 %0, %1" : "+v"(x0), "+v"(x2));
      asm("v_permlane32_swap_b32 %0, %1" : "+v"(x1), "+v"(x3));
      union { unsigned u[4]; bf16x8 v; } pa;
      pa.u[0] = x0; pa.u[1] = x1; pa.u[2] = x2; pa.u[3] = x3;
      bf16x8 vb0 = *(const bf16x8*)&vt_s[rb3][l31 * 64 + off[tt]];
      bf16x8 vb1 = *(const bf16x8*)&vt_s[rb3][(32 + l31) * 64 + off[tt]];
      __builtin_amdgcn_s_setprio(1);
      oacc[0] = __builtin_amdgcn_mfma_f32_32x32x16_bf16(pa.v, vb0, oacc[0], 0, 0, 0);
      oacc[1] = __builtin_amdgcn_mfma_f32_32x32x16_bf16(pa.v, vb1, oacc[1], 0, 0, 0);
      __builtin_amdgcn_s_setprio(0);
    }

    // all my LDS reads complete, then block-wide "done reading buf[rb3]"
    asm volatile("s_waitcnt lgkmcnt(0)" ::: "memory");
    __builtin_amdgcn_s_barrier();

    rb3 = (rb3 == 2) ? 0 : rb3 + 1;
    wb3 = (wb3 == 2) ? 0 : wb3 + 1;
  }

  // ---- epilogue: l per q-row (lane & lane+32 halves), divide, store
  float l_acc = (la[0] + la[1]) + (la[2] + la[3]);
  l_acc += __shfl_xor(l_acc, 32);
  const float linv = 1.0f / l_acc;  // lane l31 holds inv-l for q-row l31
#pragma unroll
  for (int reg = 0; reg < 16; ++reg) {
    const int base = (reg & 3) + 8 * (reg >> 2);
    const float li = __shfl(linv, base + 4 * hi);
    const int qa = q0 + w * 32 + base + 4 * hi;
    const size_t ro = (rbq + qa) * DM + h * 64 + l31;
    Oa[ro] = (ushort)f2b(oacc[0][reg] * li);
    Oa[ro + 32] = (ushort)f2b(oacc[1][reg] * li);
  }
}

// ---------------------------------------------------------------------------
// Workspace = 56 MB exactly:
//   qc,kc,vc (3*NE u16) | Qp,Kp,Vt (3*NE u16) | 4 weights (4*NW u16)
//   attn output reuses qc; mask bit-words (1 MB) reuse vc (free after V GEMM).
extern "C" void kernel_launch(void* const* d_in, const int* in_sizes, int n_in,
                              void* d_out, int out_size, void* d_ws, size_t ws_size,
                              hipStream_t stream) {
  const int* mask = (const int*)d_in[3];
  const float* bq = (const float*)d_in[5];
  const float* bk = (const float*)d_in[7];
  const float* bv = (const float*)d_in[9];
  const float* bo = (const float*)d_in[11];

  const size_t NE = (size_t)B_ * S_ * DM;  // 4M
  const size_t NW = (size_t)DM * DM;       // 1M

  ushort* qc = (ushort*)d_ws;
  ushort* kc = qc + NE;
  ushort* vc = kc + NE;
  ushort* Qp = vc + NE;
  ushort* Kp = Qp + NE;
  ushort* Vt = Kp + NE;
  ushort* Wqc = Vt + NE;
  ushort* Wkc = Wqc + NW;
  ushort* Wvc = Wkc + NW;
  ushort* Woc = Wvc + NW;
  unsigned long long* mbits = (unsigned long long*)vc;  // 131072 words = 1 MB

  Cvt7 c;
  const int sidx[7] = {0, 1, 2, 4, 6, 8, 10};
  ushort* dsts[7] = {qc, kc, vc, Wqc, Wkc, Wvc, Woc};
  for (int i = 0; i < 7; ++i) {
    c.src[i] = (const float*)d_in[sidx[i]];
    c.dst[i] = dsts[i];
    c.n[i] = (i < 3) ? (int)NE : (int)NW;
  }
  cvt_all<<<dim3(2048, 7), 256, 0, stream>>>(c);

  // Q projection pre-scaled by (1/sqrt(dk)) * log2(e) so attn uses exp2
  G3 g;
  g.A[0] = qc;  g.A[1] = kc;  g.A[2] = vc;
  g.W[0] = Wqc; g.W[1] = Wkc; g.W[2] = Wvc;
  g.bias[0] = bq; g.bias[1] = bk; g.bias[2] = bv;
  g.C[0] = Qp;  g.C[1] = Kp;  g.C[2] = Vt;
  g.scale[0] = 0.125f * 1.4426950408889634f;
  g.scale[1] = 1.0f;
  g.scale[2] = 1.0f;
  gemm_qkv<<<dim3(Mdim / 128, Ndim / 128, 3), 256, 0, stream>>>(g);

  // pack mask into vc region (V GEMM has consumed vc by now)
  mask_bits<<<(B_ * S_ * S_) / 256, 256, 0, stream>>>(mask, mbits);

  attn_mfma<<<dim3(S_ / 128, B_ * NH), 256, 0, stream>>>(Qp, Kp, Vt, mbits, qc);

  gemm128<float, 0><<<dim3(Mdim / 128, Ndim / 64), 256, 0, stream>>>(
      qc, Woc, bo, (float*)d_out, 1.0f);
}

// Round 7
// 263.935 us; speedup vs baseline: 1.1125x; 1.0226x over previous
//
#include <hip/hip_runtime.h>
#include <hip/hip_bf16.h>

#define B_   2
#define S_   2048
#define DM   1024
#define NH   16
#define DKH  64
#define Mdim 4096
#define Ndim 1024
#define Kdim 1024

typedef __attribute__((ext_vector_type(8))) short bf16x8;
typedef __attribute__((ext_vector_type(4))) short bf16x4;
typedef __attribute__((ext_vector_type(4))) float f32x4;
typedef __attribute__((ext_vector_type(16))) float f32x16;

__device__ __forceinline__ short f2b(float x) {
  union { __hip_bfloat16 h; short s; } u;
  u.h = __float2bfloat16(x);
  return u.s;
}

// async global->LDS, 16 B/lane; LDS dst = wave-uniform base + lane*16
__device__ __forceinline__ void async_copy16(const void* g, void* l) {
  __builtin_amdgcn_global_load_lds(
      (const __attribute__((address_space(1))) unsigned int*)g,
      (__attribute__((address_space(3))) unsigned int*)l, 16, 0, 0);
}
// async global->LDS, 4 B/lane; LDS dst = wave-uniform base + lane*4
__device__ __forceinline__ void async_copy4(const void* g, void* l) {
  __builtin_amdgcn_global_load_lds(
      (const __attribute__((address_space(1))) unsigned int*)g,
      (__attribute__((address_space(3))) unsigned int*)l, 4, 0, 0);
}

// ---------------------------------------------------------------------------
// Batched fp32 -> bf16 conversion (7 tensors) + mask bit-pack (8th slice).
// Mask pack: mbT[kw * (B*S) + (b*S + q)], bit j = key kw*64 + j (transposed
// for coalesced per-tile reads in attn).
struct Cvt7 {
  const float* src[7];
  ushort* dst[7];
  int n[7];
};

__global__ __launch_bounds__(256) void cvt_all(Cvt7 c, const int* __restrict__ mask,
                                               unsigned long long* __restrict__ mb) {
  const int ten = blockIdx.y;
  if (ten == 7) {
    // 8M mask ints, 2048 blocks x 16 iters x 256 threads
#pragma unroll
    for (int it = 0; it < 16; ++it) {
      const size_t i = ((size_t)blockIdx.x * 16 + it) * 256 + threadIdx.x;
      const unsigned long long bits = __ballot(mask[i] != 0);
      if ((threadIdx.x & 63) == 0) {
        const size_t word = i >> 6;          // (b*S+q)*32 + kw
        const size_t kw = word & 31;
        const size_t row = word >> 5;        // b*S + q
        mb[kw * (size_t)(B_ * S_) + row] = bits;
      }
    }
    return;
  }
  const int base = (blockIdx.x * 256 + threadIdx.x) * 8;
  if (base >= c.n[ten]) return;
  const float* s = c.src[ten] + base;
  float4 a = *(const float4*)s;
  float4 b = *(const float4*)(s + 4);
  bf16x8 r;
  r[0] = f2b(a.x); r[1] = f2b(a.y); r[2] = f2b(a.z); r[3] = f2b(a.w);
  r[4] = f2b(b.x); r[5] = f2b(b.y); r[6] = f2b(b.z); r[7] = f2b(b.w);
  *(bf16x8*)(c.dst[ten] + base) = r;
}

// ---------------------------------------------------------------------------
__device__ __forceinline__ void gstore(float* C, size_t i, float v) { C[i] = v; }
__device__ __forceinline__ void gstore(ushort* C, size_t i, float v) { C[i] = (ushort)f2b(v); }

// m97-structure core + T3/T4 pipeline: C[4096,1024] = A@W^T + bias, *scale.
// 128x128 tile, BK=32, double-buffered LDS staged via global_load_lds(16B);
// counted vmcnt(4) across raw s_barriers (never drains in main loop).
// vt=1: write head-transposed [b][h][d][s] (for V).
template <typename OutT>
__device__ __forceinline__ void gemm_core(const ushort* __restrict__ A,
                                          const ushort* __restrict__ W,
                                          const float* __restrict__ bias,
                                          OutT* __restrict__ C, float scale, int vt,
                                          ushort* a_s, ushort* b_s) {
  const int t = threadIdx.x;
  const int w = t >> 6, lane = t & 63;
  const int quad = lane >> 4, r16 = lane & 15;
  const int wr = w >> 1, wc = w & 1;
  const int row0 = blockIdx.x * 128, col0 = blockIdx.y * 128;

  const int sr = t >> 2, sc = (t & 3) * 8;
  const ushort* Ag0 = A + (size_t)(row0 + sr) * Kdim + sc;
  const ushort* Ag1 = Ag0 + (size_t)64 * Kdim;
  const ushort* Wg0 = W + (size_t)(col0 + sr) * Kdim + sc;
  const ushort* Wg1 = Wg0 + (size_t)64 * Kdim;
  const int alo0 = (w * 16) * 32;
  const int alo1 = (64 + w * 16) * 32;

  auto stg = [&](int buf, int k0) {
    ushort* ab = a_s + buf * 4096;
    ushort* bb = b_s + buf * 4096;
    async_copy16(Ag0 + k0, ab + alo0);
    async_copy16(Ag1 + k0, ab + alo1);
    async_copy16(Wg0 + k0, bb + alo0);
    async_copy16(Wg1 + k0, bb + alo1);
  };

  f32x4 acc[4][4];
#pragma unroll
  for (int mt = 0; mt < 4; ++mt)
#pragma unroll
    for (int nt = 0; nt < 4; ++nt) acc[mt][nt] = (f32x4){0.f, 0.f, 0.f, 0.f};

  stg(0, 0);
  for (int k0 = 0; k0 < Kdim; k0 += 32) {
    const int cb = (k0 >> 5) & 1;
    if (k0 + 32 < Kdim) {
      stg(cb ^ 1, k0 + 32);
      asm volatile("s_waitcnt vmcnt(4)" ::: "memory");  // tile k0 done; next in flight
    } else {
      asm volatile("s_waitcnt vmcnt(0)" ::: "memory");
    }
    __builtin_amdgcn_s_barrier();  // all waves' tile-k0 writes visible

    const int bo = cb * 4096;
    bf16x8 af[4], bfr[4];
#pragma unroll
    for (int mt = 0; mt < 4; ++mt)
      af[mt] = *(const bf16x8*)&a_s[bo + (wr * 64 + mt * 16 + r16) * 32 + quad * 8];
#pragma unroll
    for (int nt = 0; nt < 4; ++nt)
      bfr[nt] = *(const bf16x8*)&b_s[bo + (wc * 64 + nt * 16 + r16) * 32 + quad * 8];
#pragma unroll
    for (int mt = 0; mt < 4; ++mt)
#pragma unroll
      for (int nt = 0; nt < 4; ++nt)
        acc[mt][nt] = __builtin_amdgcn_mfma_f32_16x16x32_bf16(af[mt], bfr[nt],
                                                              acc[mt][nt], 0, 0, 0);

    asm volatile("s_waitcnt lgkmcnt(0)" ::: "memory");
    __builtin_amdgcn_s_barrier();  // block done reading buf cb
  }

#pragma unroll
  for (int mt = 0; mt < 4; ++mt) {
#pragma unroll
    for (int nt = 0; nt < 4; ++nt) {
      const int col = col0 + wc * 64 + nt * 16 + r16;
      const float bv = bias[col];
      const int rowb = row0 + wr * 64 + mt * 16 + quad * 4;
#pragma unroll
      for (int i = 0; i < 4; ++i) {
        const float v = (acc[mt][nt][i] + bv) * scale;
        if (vt) {
          const int row = rowb + i;
          const int bb = row >> 11, ss = row & (S_ - 1);   // row = b*S + s
          const int hh = col >> 6, dd = col & 63;          // col = h*64 + d
          gstore(C, (((size_t)bb * NH + hh) * 64 + dd) * S_ + ss, v);
        } else {
          gstore(C, (size_t)(rowb + i) * Ndim + col, v);
        }
      }
    }
  }
}

struct G3 {
  const ushort* A[3];
  const ushort* W[3];
  const float* bias[3];
  ushort* C[3];
  float scale[3];
};

__global__ __launch_bounds__(256) void gemm_qkv(G3 g) {
  __shared__ alignas(16) ushort a_s[2][128 * 32];
  __shared__ alignas(16) ushort b_s[2][128 * 32];
  const int z = blockIdx.z;
  gemm_core<ushort>(g.A[z], g.W[z], g.bias[z], g.C[z], g.scale[z], z == 2,
                    &a_s[0][0], &b_s[0][0]);
}

// ---------------------------------------------------------------------------
// O projection: 128x64 tile, BK=32, same T3/T4 pipeline (3 loads/iter).
template <typename OutT, int VT>
__global__ __launch_bounds__(256) void gemm128(const ushort* __restrict__ A,
                                               const ushort* __restrict__ W,
                                               const float* __restrict__ bias,
                                               OutT* __restrict__ C, float scale) {
  const int t = threadIdx.x;
  const int w = t >> 6, lane = t & 63;
  const int quad = lane >> 4, r16 = lane & 15;
  const int wr = w >> 1, wc = w & 1;
  const int row0 = blockIdx.x * 128, col0 = blockIdx.y * 64;

  __shared__ alignas(16) ushort a_s[2][128 * 32];
  __shared__ alignas(16) ushort b_s[2][64 * 32];

  const int sr = lane >> 2, sc = (lane & 3) * 8;
  const ushort* Ag0 = A + (size_t)(row0 + w * 32 + sr) * Kdim + sc;
  const ushort* Ag1 = Ag0 + (size_t)16 * Kdim;
  const ushort* Wg  = W + (size_t)(col0 + w * 16 + sr) * Kdim + sc;
  const int al0 = (w * 32) * 32;
  const int al1 = (w * 32 + 16) * 32;
  const int bl  = (w * 16) * 32;

  auto stg = [&](int buf, int k0) {
    async_copy16(Ag0 + k0, &a_s[buf][al0]);
    async_copy16(Ag1 + k0, &a_s[buf][al1]);
    async_copy16(Wg + k0, &b_s[buf][bl]);
  };

  f32x4 acc[4][2];
#pragma unroll
  for (int mt = 0; mt < 4; ++mt)
#pragma unroll
    for (int nt = 0; nt < 2; ++nt) acc[mt][nt] = (f32x4){0.f, 0.f, 0.f, 0.f};

  stg(0, 0);
  for (int k0 = 0; k0 < Kdim; k0 += 32) {
    const int cb = (k0 >> 5) & 1;
    if (k0 + 32 < Kdim) {
      stg(cb ^ 1, k0 + 32);
      asm volatile("s_waitcnt vmcnt(3)" ::: "memory");
    } else {
      asm volatile("s_waitcnt vmcnt(0)" ::: "memory");
    }
    __builtin_amdgcn_s_barrier();

    bf16x8 af[4], bfr[2];
#pragma unroll
    for (int mt = 0; mt < 4; ++mt)
      af[mt] = *(const bf16x8*)&a_s[cb][(wr * 64 + mt * 16 + r16) * 32 + quad * 8];
#pragma unroll
    for (int nt = 0; nt < 2; ++nt)
      bfr[nt] = *(const bf16x8*)&b_s[cb][(wc * 32 + nt * 16 + r16) * 32 + quad * 8];
#pragma unroll
    for (int mt = 0; mt < 4; ++mt)
#pragma unroll
      for (int nt = 0; nt < 2; ++nt)
        acc[mt][nt] = __builtin_amdgcn_mfma_f32_16x16x32_bf16(af[mt], bfr[nt],
                                                              acc[mt][nt], 0, 0, 0);

    asm volatile("s_waitcnt lgkmcnt(0)" ::: "memory");
    __builtin_amdgcn_s_barrier();
  }

#pragma unroll
  for (int mt = 0; mt < 4; ++mt) {
#pragma unroll
    for (int nt = 0; nt < 2; ++nt) {
      const int col = col0 + wc * 32 + nt * 16 + r16;
      const float bv = bias[col];
      const int rowb = row0 + wr * 64 + mt * 16 + quad * 4;
#pragma unroll
      for (int i = 0; i < 4; ++i) {
        const float v = (acc[mt][nt][i] + bv) * scale;
        if (VT) {
          const int row = rowb + i;
          const int bb = row >> 11, ss = row & (S_ - 1);
          const int hh = col >> 6, dd = col & 63;
          gstore(C, (((size_t)bb * NH + hh) * 64 + dd) * S_ + ss, v);
        } else {
          gstore(C, (size_t)(rowb + i) * Ndim + col, v);
        }
      }
    }
  }
}

// ---------------------------------------------------------------------------
// MFMA flash attention, 32x32x16, swapped QK^T, permlane exchange.
// T3/T4 triple-buffered pipeline (counted vmcnt 10/5/0, raw barriers).
// T1 at head granularity: bijective bid decode groups all 16 q-blocks of a
// head on one XCD (4 heads/XCD, K+V = 2 MB <= 4 MB XCD L2) -> K/V HBM
// re-fetch eliminated. Mask bias via v_bfe_i32 sign-extract.
__global__ __launch_bounds__(256, 2) void attn_mfma(const ushort* __restrict__ Qp,
                                                    const ushort* __restrict__ Kp,
                                                    const ushort* __restrict__ Vt,
                                                    const unsigned long long* __restrict__ mbT,
                                                    ushort* __restrict__ Oa) {
  // bid = xcd + 8*m; head-group = xcd*4 + (m&3); q-block = m>>2
  const int bid = blockIdx.x;
  const int xcd = bid & 7, m = bid >> 3;
  const int bh = xcd * 4 + (m & 3);
  const int b = bh >> 4, h = bh & 15;
  const int q0 = (m >> 2) * 128;
  const int t = threadIdx.x;
  const int w = t >> 6, lane = t & 63;
  const int l31 = lane & 31, hi = lane >> 5, l7 = lane & 7;
  const size_t rbq = (size_t)b * S_;

  // [row][chunk] with 8-elem (16B) chunks XOR-swizzled: slot = c ^ (row&7)
  __shared__ alignas(16) ushort k_s[3][64 * 64];   // [key][dk]
  __shared__ alignas(16) ushort vt_s[3][64 * 64];  // [dk][key]
  __shared__ alignas(8) unsigned long long mask_lds[3][128];

  // Q B-frags: qf[s] holds Q[qrow][dk = 16s + 8hi + j]
  const int qrow = q0 + w * 32 + l31;
  const ushort* qp = Qp + (rbq + qrow) * DM + h * 64 + hi * 8;
  bf16x8 qf[4];
#pragma unroll
  for (int s = 0; s < 4; ++s) qf[s] = *(const bf16x8*)(qp + 16 * s);

  // staging: lane l -> LDS row base+(l>>3), slot l&7; global chunk pre-swizzled
  const int srow = lane >> 3;
  const int schk = l7 ^ srow;
  const int kr0 = w * 16 + srow;
  const ushort* kg0 = Kp + (rbq + kr0) * DM + h * 64 + schk * 8;
  const ushort* kg1 = kg0 + (size_t)8 * DM;
  const ushort* vg0 = Vt + ((size_t)bh * 64 + kr0) * S_ + schk * 8;
  const ushort* vg1 = vg0 + (size_t)8 * S_;
  const int lo0 = (w * 16) * 64;
  const int lo1 = (w * 16 + 8) * 64;
  // mask words: 1 KB per tile (128 q-rows x 8B); thread t loads u32 slot t
  const uint* mgsrc = (const uint*)mbT + ((size_t)b * S_ + q0) * 2 + t;

  auto stage = [&](int buf, int ktg) {
    async_copy16(kg0 + (size_t)ktg * DM, &k_s[buf][lo0]);
    async_copy16(kg1 + (size_t)ktg * DM, &k_s[buf][lo1]);
    async_copy16(vg0 + ktg, &vt_s[buf][lo0]);
    async_copy16(vg1 + ktg, &vt_s[buf][lo1]);
    async_copy4(mgsrc + (size_t)(ktg >> 6) * (2 * B_ * S_),
                (char*)&mask_lds[0][0] + buf * 1024 + w * 256);
  };

  // swizzled read offsets for chunk c = 2x + hi (reader row&7 == l7)
  int off[4];
#pragma unroll
  for (int x = 0; x < 4; ++x) off[x] = ((2 * x + hi) ^ l7) * 8;

  f32x16 oacc[2];
#pragma unroll
  for (int i = 0; i < 16; ++i) { oacc[0][i] = 0.f; oacc[1][i] = 0.f; }
  float la[4] = {0.f, 0.f, 0.f, 0.f};

  // prologue: stage tiles 0,1 into bufs 0,1 (10 VMEM ops in flight)
  stage(0, 0);
  stage(1, 64);

  int rb3 = 0, wb3 = 2;
  for (int kt = 0; kt < S_; kt += 64) {
    // issue tile kt+128 into the 3rd buffer (its readers finished two
    // iterations ago at the end-of-iter barrier)
    if (kt + 128 < S_) stage(wb3, kt + 128);

    // counted wait: tile kt's 5 ops done; newer 10 stay in flight
    if (kt + 128 < S_) {
      asm volatile("s_waitcnt vmcnt(10)" ::: "memory");
    } else if (kt + 64 < S_) {
      asm volatile("s_waitcnt vmcnt(5)" ::: "memory");
    } else {
      asm volatile("s_waitcnt vmcnt(0)" ::: "memory");
    }
    __builtin_amdgcn_s_barrier();  // all waves' tile-kt writes visible

    // mask word for this lane's q-row, keys [kt, kt+64)
    const unsigned long long mw = mask_lds[rb3][w * 32 + l31];
    const unsigned long long msh = mw >> (4 * hi);
    int inv[2];
    inv[0] = ~(int)(unsigned)msh;
    inv[1] = ~(int)(unsigned)(msh >> 32);

    // ---- S^T = K Q^T with mask bias folded into C-init:
    // sacc[g][reg] = (keep ? 0 : -200); key = 32g + (reg&3)+8*(reg>>2)+4hi
    bf16x8 kf[2][4];
#pragma unroll
    for (int g = 0; g < 2; ++g)
#pragma unroll
      for (int s = 0; s < 4; ++s)
        kf[g][s] = *(const bf16x8*)&k_s[rb3][(32 * g + l31) * 64 + off[s]];

    f32x16 sacc[2];
#pragma unroll
    for (int g = 0; g < 2; ++g)
#pragma unroll
      for (int reg = 0; reg < 16; ++reg) {
        const int base = (reg & 3) + 8 * (reg >> 2);
        const int sm = __builtin_amdgcn_sbfe(inv[g], base, 1);  // keep?0:-1
        sacc[g][reg] = __int_as_float(sm & 0xC3480000);         // 0 or -200.0f
      }

    __builtin_amdgcn_s_setprio(1);
#pragma unroll
    for (int g = 0; g < 2; ++g)
#pragma unroll
      for (int s = 0; s < 4; ++s)
        sacc[g] = __builtin_amdgcn_mfma_f32_32x32x16_bf16(kf[g][s], qf[s], sacc[g], 0, 0, 0);
    __builtin_amdgcn_s_setprio(0);

    // ---- exp2 (Q carries log2e; masked keys = exp2(s-200) -> 0), pack pairs
    unsigned pd[2][8];
#pragma unroll
    for (int g = 0; g < 2; ++g) {
      float p[16];
#pragma unroll
      for (int reg = 0; reg < 16; ++reg) {
        float e;
        asm("v_exp_f32 %0, %1" : "=v"(e) : "v"(sacc[g][reg]));
        p[reg] = e;
      }
#pragma unroll
      for (int reg = 0; reg < 16; ++reg) la[reg & 3] += p[reg];
#pragma unroll
      for (int r = 0; r < 8; ++r) {
        unsigned dst;
        asm("v_cvt_pk_bf16_f32 %0, %1, %2" : "=v"(dst) : "v"(p[2 * r]), "v"(p[2 * r + 1]));
        pd[g][r] = dst;
      }
    }

    // ---- permlane exchange -> PV A-frags; O += P V
#pragma unroll
    for (int tt = 0; tt < 4; ++tt) {
      const int g = tt >> 1, tp = tt & 1;
      unsigned x0 = pd[g][4 * tp + 0], x2 = pd[g][4 * tp + 2];
      unsigned x1 = pd[g][4 * tp + 1], x3 = pd[g][4 * tp + 3];
      asm("v_permlane32_swap_b32 %0, %1" : "+v"(x0), "+v"(x2));
      asm("v_permlane32_swap_b32 %0, %1" : "+v"(x1), "+v"(x3));
      union { unsigned u[4]; bf16x8 v; } pa;
      pa.u[0] = x0; pa.u[1] = x1; pa.u[2] = x2; pa.u[3] = x3;
      bf16x8 vb0 = *(const bf16x8*)&vt_s[rb3][l31 * 64 + off[tt]];
      bf16x8 vb1 = *(const bf16x8*)&vt_s[rb3][(32 + l31) * 64 + off[tt]];
      __builtin_amdgcn_s_setprio(1);
      oacc[0] = __builtin_amdgcn_mfma_f32_32x32x16_bf16(pa.v, vb0, oacc[0], 0, 0, 0);
      oacc[1] = __builtin_amdgcn_mfma_f32_32x32x16_bf16(pa.v, vb1, oacc[1], 0, 0, 0);
      __builtin_amdgcn_s_setprio(0);
    }

    // all my LDS reads complete, then block-wide "done reading buf[rb3]"
    asm volatile("s_waitcnt lgkmcnt(0)" ::: "memory");
    __builtin_amdgcn_s_barrier();

    rb3 = (rb3 == 2) ? 0 : rb3 + 1;
    wb3 = (wb3 == 2) ? 0 : wb3 + 1;
  }

  // ---- epilogue: l per q-row (lane & lane+32 halves), divide, store
  float l_acc = (la[0] + la[1]) + (la[2] + la[3]);
  l_acc += __shfl_xor(l_acc, 32);
  const float linv = 1.0f / l_acc;  // lane l31 holds inv-l for q-row l31
#pragma unroll
  for (int reg = 0; reg < 16; ++reg) {
    const int base = (reg & 3) + 8 * (reg >> 2);
    const float li = __shfl(linv, base + 4 * hi);
    const int qa = q0 + w * 32 + base + 4 * hi;
    const size_t ro = (rbq + qa) * DM + h * 64 + l31;
    Oa[ro] = (ushort)f2b(oacc[0][reg] * li);
    Oa[ro + 32] = (ushort)f2b(oacc[1][reg] * li);
  }
}

// ---------------------------------------------------------------------------
// Workspace = 56 MB exactly:
//   qc,kc,vc (3*NE u16) | Qp,Kp,Vt (3*NE u16) | 4 weights (4*NW u16)
//   attn output reuses qc; mask bit-words (1 MB) live at the head of d_out
//   (free until the final O-projection writes it — after attn consumed them).
extern "C" void kernel_launch(void* const* d_in, const int* in_sizes, int n_in,
                              void* d_out, int out_size, void* d_ws, size_t ws_size,
                              hipStream_t stream) {
  const int* mask = (const int*)d_in[3];
  const float* bq = (const float*)d_in[5];
  const float* bk = (const float*)d_in[7];
  const float* bv = (const float*)d_in[9];
  const float* bo = (const float*)d_in[11];

  const size_t NE = (size_t)B_ * S_ * DM;  // 4M
  const size_t NW = (size_t)DM * DM;       // 1M

  ushort* qc = (ushort*)d_ws;
  ushort* kc = qc + NE;
  ushort* vc = kc + NE;
  ushort* Qp = vc + NE;
  ushort* Kp = Qp + NE;
  ushort* Vt = Kp + NE;
  ushort* Wqc = Vt + NE;
  ushort* Wkc = Wqc + NW;
  ushort* Wvc = Wkc + NW;
  ushort* Woc = Wvc + NW;
  unsigned long long* mbits = (unsigned long long*)d_out;  // 131072 words = 1 MB

  Cvt7 c;
  const int sidx[7] = {0, 1, 2, 4, 6, 8, 10};
  ushort* dsts[7] = {qc, kc, vc, Wqc, Wkc, Wvc, Woc};
  for (int i = 0; i < 7; ++i) {
    c.src[i] = (const float*)d_in[sidx[i]];
    c.dst[i] = dsts[i];
    c.n[i] = (i < 3) ? (int)NE : (int)NW;
  }
  cvt_all<<<dim3(2048, 8), 256, 0, stream>>>(c, mask, mbits);

  // Q projection pre-scaled by (1/sqrt(dk)) * log2(e) so attn uses exp2
  G3 g;
  g.A[0] = qc;  g.A[1] = kc;  g.A[2] = vc;
  g.W[0] = Wqc; g.W[1] = Wkc; g.W[2] = Wvc;
  g.bias[0] = bq; g.bias[1] = bk; g.bias[2] = bv;
  g.C[0] = Qp;  g.C[1] = Kp;  g.C[2] = Vt;
  g.scale[0] = 0.125f * 1.4426950408889634f;
  g.scale[1] = 1.0f;
  g.scale[2] = 1.0f;
  gemm_qkv<<<dim3(Mdim / 128, Ndim / 128, 3), 256, 0, stream>>>(g);

  attn_mfma<<<dim3(512), 256, 0, stream>>>(Qp, Kp, Vt, mbits, qc);

  gemm128<float, 0><<<dim3(Mdim / 128, Ndim / 64), 256, 0, stream>>>(
      qc, Woc, bo, (float*)d_out, 1.0f);
}

// Round 8
// 255.085 us; speedup vs baseline: 1.1511x; 1.0347x over previous
//
#include <hip/hip_runtime.h>
#include <hip/hip_bf16.h>

#define B_   2
#define S_   2048
#define DM   1024
#define NH   16
#define DKH  64
#define Mdim 4096
#define Ndim 1024
#define Kdim 1024

typedef __attribute__((ext_vector_type(8))) short bf16x8;
typedef __attribute__((ext_vector_type(4))) short bf16x4;
typedef __attribute__((ext_vector_type(4))) float f32x4;
typedef __attribute__((ext_vector_type(16))) float f32x16;

__device__ __forceinline__ short f2b(float x) {
  union { __hip_bfloat16 h; short s; } u;
  u.h = __float2bfloat16(x);
  return u.s;
}

// async global->LDS, 16 B/lane; LDS dst = wave-uniform base + lane*16
__device__ __forceinline__ void async_copy16(const void* g, void* l) {
  __builtin_amdgcn_global_load_lds(
      (const __attribute__((address_space(1))) unsigned int*)g,
      (__attribute__((address_space(3))) unsigned int*)l, 16, 0, 0);
}
// async global->LDS, 4 B/lane; LDS dst = wave-uniform base + lane*4
__device__ __forceinline__ void async_copy4(const void* g, void* l) {
  __builtin_amdgcn_global_load_lds(
      (const __attribute__((address_space(1))) unsigned int*)g,
      (__attribute__((address_space(3))) unsigned int*)l, 4, 0, 0);
}

// ---------------------------------------------------------------------------
// Batched fp32 -> bf16 conversion (7 tensors) + mask bit-pack (8th slice).
// Mask pack: mbT[kw * (B*S) + (b*S + q)], bit j = key kw*64 + j.
struct Cvt7 {
  const float* src[7];
  ushort* dst[7];
  int n[7];
};

__global__ __launch_bounds__(256) void cvt_all(Cvt7 c, const int* __restrict__ mask,
                                               unsigned long long* __restrict__ mb) {
  const int ten = blockIdx.y;
  if (ten == 7) {
#pragma unroll
    for (int it = 0; it < 16; ++it) {
      const size_t i = ((size_t)blockIdx.x * 16 + it) * 256 + threadIdx.x;
      const unsigned long long bits = __ballot(mask[i] != 0);
      if ((threadIdx.x & 63) == 0) {
        const size_t word = i >> 6;          // (b*S+q)*32 + kw
        const size_t kw = word & 31;
        const size_t row = word >> 5;        // b*S + q
        mb[kw * (size_t)(B_ * S_) + row] = bits;
      }
    }
    return;
  }
  const int base = (blockIdx.x * 256 + threadIdx.x) * 8;
  if (base >= c.n[ten]) return;
  const float* s = c.src[ten] + base;
  float4 a = *(const float4*)s;
  float4 b = *(const float4*)(s + 4);
  bf16x8 r;
  r[0] = f2b(a.x); r[1] = f2b(a.y); r[2] = f2b(a.z); r[3] = f2b(a.w);
  r[4] = f2b(b.x); r[5] = f2b(b.y); r[6] = f2b(b.z); r[7] = f2b(b.w);
  *(bf16x8*)(c.dst[ten] + base) = r;
}

// ---------------------------------------------------------------------------
__device__ __forceinline__ void gstore(float* C, size_t i, float v) { C[i] = v; }
__device__ __forceinline__ void gstore(ushort* C, size_t i, float v) { C[i] = (ushort)f2b(v); }

// C[4096,1024] = A@W^T + bias, *scale. 128x128 tile, BK=32, TRIPLE-buffered
// LDS via global_load_lds(16B); single barrier/iter, steady vmcnt(4).
// vt=1: epilogue transposes the tile through LDS, then stores [b][h][d][s]
// as coalesced bf16x8 runs (fixes 2B-scattered V store).
template <typename OutT>
__device__ __forceinline__ void gemm_core(const ushort* __restrict__ A,
                                          const ushort* __restrict__ W,
                                          const float* __restrict__ bias,
                                          OutT* __restrict__ C, float scale, int vt,
                                          ushort* smem) {
  const int t = threadIdx.x;
  const int w = t >> 6, lane = t & 63;
  const int quad = lane >> 4, r16 = lane & 15;
  const int wr = w >> 1, wc = w & 1;
  const int row0 = blockIdx.x * 128, col0 = blockIdx.y * 128;

  ushort* a_s = smem;            // 3 bufs x 4096
  ushort* b_s = smem + 12288;    // 3 bufs x 4096

  const int sr = t >> 2, sc = (t & 3) * 8;
  const ushort* Ag0 = A + (size_t)(row0 + sr) * Kdim + sc;
  const ushort* Ag1 = Ag0 + (size_t)64 * Kdim;
  const ushort* Wg0 = W + (size_t)(col0 + sr) * Kdim + sc;
  const ushort* Wg1 = Wg0 + (size_t)64 * Kdim;
  const int alo0 = (w * 16) * 32;
  const int alo1 = (64 + w * 16) * 32;

  auto stg = [&](int buf, int k0) {
    ushort* ab = a_s + buf * 4096;
    ushort* bb = b_s + buf * 4096;
    async_copy16(Ag0 + k0, ab + alo0);
    async_copy16(Ag1 + k0, ab + alo1);
    async_copy16(Wg0 + k0, bb + alo0);
    async_copy16(Wg1 + k0, bb + alo1);
  };

  f32x4 acc[4][4];
#pragma unroll
  for (int mt = 0; mt < 4; ++mt)
#pragma unroll
    for (int nt = 0; nt < 4; ++nt) acc[mt][nt] = (f32x4){0.f, 0.f, 0.f, 0.f};

  stg(0, 0);
  stg(1, 32);
  for (int k0 = 0; k0 < Kdim; k0 += 32) {
    const int cb = (k0 >> 5) % 3;
    if (k0 + 32 < Kdim) {
      asm volatile("s_waitcnt vmcnt(4)" ::: "memory");   // buf cb done; next in flight
    } else {
      asm volatile("s_waitcnt vmcnt(0)" ::: "memory");
    }
    asm volatile("s_waitcnt lgkmcnt(0)" ::: "memory");   // my old reads drained
    __builtin_amdgcn_s_barrier();                        // writes visible + WAR safe
    if (k0 + 64 < Kdim) stg((cb + 2) % 3, k0 + 64);      // overwrite retired buf

    const int bo = cb * 4096;
    bf16x8 af[4], bfr[4];
#pragma unroll
    for (int mt = 0; mt < 4; ++mt)
      af[mt] = *(const bf16x8*)&a_s[bo + (wr * 64 + mt * 16 + r16) * 32 + quad * 8];
#pragma unroll
    for (int nt = 0; nt < 4; ++nt)
      bfr[nt] = *(const bf16x8*)&b_s[bo + (wc * 64 + nt * 16 + r16) * 32 + quad * 8];
#pragma unroll
    for (int mt = 0; mt < 4; ++mt)
#pragma unroll
      for (int nt = 0; nt < 4; ++nt)
        acc[mt][nt] = __builtin_amdgcn_mfma_f32_16x16x32_bf16(af[mt], bfr[nt],
                                                              acc[mt][nt], 0, 0, 0);
  }

  if (vt) {
    // ---- transpose through LDS: ts[col][136] (b64 writes, 16B-aligned reads)
    __syncthreads();                 // everyone done with staging buffers
    ushort* ts = smem;               // 128*136 = 17408 ushorts <= 24576
#pragma unroll
    for (int mt = 0; mt < 4; ++mt) {
#pragma unroll
      for (int nt = 0; nt < 4; ++nt) {
        const int col_l = wc * 64 + nt * 16 + r16;
        const float bv = bias[col0 + col_l];
        const int row_l = wr * 64 + mt * 16 + quad * 4;
        bf16x4 pk;
#pragma unroll
        for (int i = 0; i < 4; ++i) pk[i] = f2b((acc[mt][nt][i] + bv) * scale);
        *(bf16x4*)&ts[col_l * 136 + row_l] = pk;
      }
    }
    __syncthreads();
    // read back: thread -> ss-chunk (t&15)*8, col (t>>4) + 16*pass
    const int cch = (t & 15) * 8;
    const int rb = t >> 4;
#pragma unroll
    for (int pass = 0; pass < 8; ++pass) {
      const int col_l = rb + pass * 16;
      const bf16x8 v = *(const bf16x8*)&ts[col_l * 136 + cch];
      const int col_g = col0 + col_l;
      const int hh = col_g >> 6, dd = col_g & 63;
      const int row_g = row0 + cch;
      const int bb = row_g >> 11, ss = row_g & (S_ - 1);
      *(bf16x8*)&((ushort*)C)[(((size_t)bb * NH + hh) * 64 + dd) * S_ + ss] = v;
    }
    return;
  }

#pragma unroll
  for (int mt = 0; mt < 4; ++mt) {
#pragma unroll
    for (int nt = 0; nt < 4; ++nt) {
      const int col = col0 + wc * 64 + nt * 16 + r16;
      const float bv = bias[col];
      const int rowb = row0 + wr * 64 + mt * 16 + quad * 4;
#pragma unroll
      for (int i = 0; i < 4; ++i) {
        const float v = (acc[mt][nt][i] + bv) * scale;
        gstore(C, (size_t)(rowb + i) * Ndim + col, v);
      }
    }
  }
}

struct G3 {
  const ushort* A[3];
  const ushort* W[3];
  const float* bias[3];
  ushort* C[3];
  float scale[3];
};

__global__ __launch_bounds__(256) void gemm_qkv(G3 g) {
  __shared__ alignas(16) ushort smem[24576];  // 48 KB: staging (3-buf) / transpose
  const int z = blockIdx.z;
  gemm_core<ushort>(g.A[z], g.W[z], g.bias[z], g.C[z], g.scale[z], z == 2, smem);
}

// ---------------------------------------------------------------------------
// O projection: 128x64 tile, BK=32, triple-buffered, single barrier/iter.
template <typename OutT>
__global__ __launch_bounds__(256) void gemm128(const ushort* __restrict__ A,
                                               const ushort* __restrict__ W,
                                               const float* __restrict__ bias,
                                               OutT* __restrict__ C, float scale) {
  const int t = threadIdx.x;
  const int w = t >> 6, lane = t & 63;
  const int quad = lane >> 4, r16 = lane & 15;
  const int wr = w >> 1, wc = w & 1;
  const int row0 = blockIdx.x * 128, col0 = blockIdx.y * 64;

  __shared__ alignas(16) ushort smem[18432];  // 36 KB: A 3x4096 | B 3x2048
  ushort* a_s = smem;
  ushort* b_s = smem + 12288;

  const int sr = lane >> 2, sc = (lane & 3) * 8;
  const ushort* Ag0 = A + (size_t)(row0 + w * 32 + sr) * Kdim + sc;
  const ushort* Ag1 = Ag0 + (size_t)16 * Kdim;
  const ushort* Wg  = W + (size_t)(col0 + w * 16 + sr) * Kdim + sc;
  const int al0 = (w * 32) * 32;
  const int al1 = (w * 32 + 16) * 32;
  const int bl  = (w * 16) * 32;

  auto stg = [&](int buf, int k0) {
    async_copy16(Ag0 + k0, &a_s[buf * 4096 + al0]);
    async_copy16(Ag1 + k0, &a_s[buf * 4096 + al1]);
    async_copy16(Wg + k0, &b_s[buf * 2048 + bl]);
  };

  f32x4 acc[4][2];
#pragma unroll
  for (int mt = 0; mt < 4; ++mt)
#pragma unroll
    for (int nt = 0; nt < 2; ++nt) acc[mt][nt] = (f32x4){0.f, 0.f, 0.f, 0.f};

  stg(0, 0);
  stg(1, 32);
  for (int k0 = 0; k0 < Kdim; k0 += 32) {
    const int cb = (k0 >> 5) % 3;
    if (k0 + 32 < Kdim) {
      asm volatile("s_waitcnt vmcnt(3)" ::: "memory");
    } else {
      asm volatile("s_waitcnt vmcnt(0)" ::: "memory");
    }
    asm volatile("s_waitcnt lgkmcnt(0)" ::: "memory");
    __builtin_amdgcn_s_barrier();
    if (k0 + 64 < Kdim) stg((cb + 2) % 3, k0 + 64);

    bf16x8 af[4], bfr[2];
#pragma unroll
    for (int mt = 0; mt < 4; ++mt)
      af[mt] = *(const bf16x8*)&a_s[cb * 4096 + (wr * 64 + mt * 16 + r16) * 32 + quad * 8];
#pragma unroll
    for (int nt = 0; nt < 2; ++nt)
      bfr[nt] = *(const bf16x8*)&b_s[cb * 2048 + (wc * 32 + nt * 16 + r16) * 32 + quad * 8];
#pragma unroll
    for (int mt = 0; mt < 4; ++mt)
#pragma unroll
      for (int nt = 0; nt < 2; ++nt)
        acc[mt][nt] = __builtin_amdgcn_mfma_f32_16x16x32_bf16(af[mt], bfr[nt],
                                                              acc[mt][nt], 0, 0, 0);
  }

#pragma unroll
  for (int mt = 0; mt < 4; ++mt) {
#pragma unroll
    for (int nt = 0; nt < 2; ++nt) {
      const int col = col0 + wc * 32 + nt * 16 + r16;
      const float bv = bias[col];
      const int rowb = row0 + wr * 64 + mt * 16 + quad * 4;
#pragma unroll
      for (int i = 0; i < 4; ++i) {
        const float v = (acc[mt][nt][i] + bv) * scale;
        gstore(C, (size_t)(rowb + i) * Ndim + col, v);
      }
    }
  }
}

// ---------------------------------------------------------------------------
// MFMA flash attention, 32x32x16, swapped QK^T, permlane exchange.
// Triple-buffered, SINGLE barrier per tile (lgkm folded into top barrier,
// stage issued after it), steady vmcnt(5). XCD head-grouping (L2-resident
// K/V). Mask bias folded into QK^T C-init.
__global__ __launch_bounds__(256, 2) void attn_mfma(const ushort* __restrict__ Qp,
                                                    const ushort* __restrict__ Kp,
                                                    const ushort* __restrict__ Vt,
                                                    const unsigned long long* __restrict__ mbT,
                                                    ushort* __restrict__ Oa) {
  // bid = xcd + 8*m; head-group = xcd*4 + (m&3); q-block = m>>2
  const int bid = blockIdx.x;
  const int xcd = bid & 7, m = bid >> 3;
  const int bh = xcd * 4 + (m & 3);
  const int b = bh >> 4, h = bh & 15;
  const int q0 = (m >> 2) * 128;
  const int t = threadIdx.x;
  const int w = t >> 6, lane = t & 63;
  const int l31 = lane & 31, hi = lane >> 5, l7 = lane & 7;
  const size_t rbq = (size_t)b * S_;

  __shared__ alignas(16) ushort k_s[3][64 * 64];   // [key][dk], chunks XOR-swz
  __shared__ alignas(16) ushort vt_s[3][64 * 64];  // [dk][key]
  __shared__ alignas(8) unsigned long long mask_lds[3][128];

  const int qrow = q0 + w * 32 + l31;
  const ushort* qp = Qp + (rbq + qrow) * DM + h * 64 + hi * 8;
  bf16x8 qf[4];
#pragma unroll
  for (int s = 0; s < 4; ++s) qf[s] = *(const bf16x8*)(qp + 16 * s);

  const int srow = lane >> 3;
  const int schk = l7 ^ srow;
  const int kr0 = w * 16 + srow;
  const ushort* kg0 = Kp + (rbq + kr0) * DM + h * 64 + schk * 8;
  const ushort* kg1 = kg0 + (size_t)8 * DM;
  const ushort* vg0 = Vt + ((size_t)bh * 64 + kr0) * S_ + schk * 8;
  const ushort* vg1 = vg0 + (size_t)8 * S_;
  const int lo0 = (w * 16) * 64;
  const int lo1 = (w * 16 + 8) * 64;
  const uint* mgsrc = (const uint*)mbT + ((size_t)b * S_ + q0) * 2 + t;

  auto stage = [&](int buf, int ktg) {
    async_copy16(kg0 + (size_t)ktg * DM, &k_s[buf][lo0]);
    async_copy16(kg1 + (size_t)ktg * DM, &k_s[buf][lo1]);
    async_copy16(vg0 + ktg, &vt_s[buf][lo0]);
    async_copy16(vg1 + ktg, &vt_s[buf][lo1]);
    async_copy4(mgsrc + (size_t)(ktg >> 6) * (2 * B_ * S_),
                (char*)&mask_lds[0][0] + buf * 1024 + w * 256);
  };

  int off[4];
#pragma unroll
  for (int x = 0; x < 4; ++x) off[x] = ((2 * x + hi) ^ l7) * 8;

  f32x16 oacc[2];
#pragma unroll
  for (int i = 0; i < 16; ++i) { oacc[0][i] = 0.f; oacc[1][i] = 0.f; }
  float la[4] = {0.f, 0.f, 0.f, 0.f};

  stage(0, 0);
  stage(1, 64);

  int rb3 = 0, wb3 = 2;
  for (int kt = 0; kt < S_; kt += 64) {
    // counted wait: tile kt's 5 ops done; next tile's 5 stay in flight
    if (kt + 64 < S_) {
      asm volatile("s_waitcnt vmcnt(5)" ::: "memory");
    } else {
      asm volatile("s_waitcnt vmcnt(0)" ::: "memory");
    }
    asm volatile("s_waitcnt lgkmcnt(0)" ::: "memory");  // my old LDS reads drained
    __builtin_amdgcn_s_barrier();  // tile-kt writes visible; WAR-safe to restage
    if (kt + 128 < S_) stage(wb3, kt + 128);

    const unsigned long long mw = mask_lds[rb3][w * 32 + l31];
    const unsigned long long msh = mw >> (4 * hi);
    int inv[2];
    inv[0] = ~(int)(unsigned)msh;
    inv[1] = ~(int)(unsigned)(msh >> 32);

    bf16x8 kf[2][4];
#pragma unroll
    for (int g = 0; g < 2; ++g)
#pragma unroll
      for (int s = 0; s < 4; ++s)
        kf[g][s] = *(const bf16x8*)&k_s[rb3][(32 * g + l31) * 64 + off[s]];

    f32x16 sacc[2];
#pragma unroll
    for (int g = 0; g < 2; ++g)
#pragma unroll
      for (int reg = 0; reg < 16; ++reg) {
        const int base = (reg & 3) + 8 * (reg >> 2);
        const int sm = __builtin_amdgcn_sbfe(inv[g], base, 1);  // keep?0:-1
        sacc[g][reg] = __int_as_float(sm & 0xC3480000);         // 0 or -200.0f
      }

    __builtin_amdgcn_s_setprio(1);
#pragma unroll
    for (int g = 0; g < 2; ++g)
#pragma unroll
      for (int s = 0; s < 4; ++s)
        sacc[g] = __builtin_amdgcn_mfma_f32_32x32x16_bf16(kf[g][s], qf[s], sacc[g], 0, 0, 0);
    __builtin_amdgcn_s_setprio(0);

    unsigned pd[2][8];
#pragma unroll
    for (int g = 0; g < 2; ++g) {
      float p[16];
#pragma unroll
      for (int reg = 0; reg < 16; ++reg) {
        float e;
        asm("v_exp_f32 %0, %1" : "=v"(e) : "v"(sacc[g][reg]));
        p[reg] = e;
      }
#pragma unroll
      for (int reg = 0; reg < 16; ++reg) la[reg & 3] += p[reg];
#pragma unroll
      for (int r = 0; r < 8; ++r) {
        unsigned dst;
        asm("v_cvt_pk_bf16_f32 %0, %1, %2" : "=v"(dst) : "v"(p[2 * r]), "v"(p[2 * r + 1]));
        pd[g][r] = dst;
      }
    }

#pragma unroll
    for (int tt = 0; tt < 4; ++tt) {
      const int g = tt >> 1, tp = tt & 1;
      unsigned x0 = pd[g][4 * tp + 0], x2 = pd[g][4 * tp + 2];
      unsigned x1 = pd[g][4 * tp + 1], x3 = pd[g][4 * tp + 3];
      asm("v_permlane32_swap_b32 %0, %1" : "+v"(x0), "+v"(x2));
      asm("v_permlane32_swap_b32 %0, %1" : "+v"(x1), "+v"(x3));
      union { unsigned u[4]; bf16x8 v; } pa;
      pa.u[0] = x0; pa.u[1] = x1; pa.u[2] = x2; pa.u[3] = x3;
      bf16x8 vb0 = *(const bf16x8*)&vt_s[rb3][l31 * 64 + off[tt]];
      bf16x8 vb1 = *(const bf16x8*)&vt_s[rb3][(32 + l31) * 64 + off[tt]];
      __builtin_amdgcn_s_setprio(1);
      oacc[0] = __builtin_amdgcn_mfma_f32_32x32x16_bf16(pa.v, vb0, oacc[0], 0, 0, 0);
      oacc[1] = __builtin_amdgcn_mfma_f32_32x32x16_bf16(pa.v, vb1, oacc[1], 0, 0, 0);
      __builtin_amdgcn_s_setprio(0);
    }

    rb3 = (rb3 == 2) ? 0 : rb3 + 1;
    wb3 = (wb3 == 2) ? 0 : wb3 + 1;
  }

  // ---- epilogue
  float l_acc = (la[0] + la[1]) + (la[2] + la[3]);
  l_acc += __shfl_xor(l_acc, 32);
  const float linv = 1.0f / l_acc;
#pragma unroll
  for (int reg = 0; reg < 16; ++reg) {
    const int base = (reg & 3) + 8 * (reg >> 2);
    const float li = __shfl(linv, base + 4 * hi);
    const int qa = q0 + w * 32 + base + 4 * hi;
    const size_t ro = (rbq + qa) * DM + h * 64 + l31;
    Oa[ro] = (ushort)f2b(oacc[0][reg] * li);
    Oa[ro + 32] = (ushort)f2b(oacc[1][reg] * li);
  }
}

// ---------------------------------------------------------------------------
// Workspace = 56 MB exactly:
//   qc,kc,vc (3*NE u16) | Qp,Kp,Vt (3*NE u16) | 4 weights (4*NW u16)
//   attn output reuses qc; mask bit-words (1 MB) live at the head of d_out.
extern "C" void kernel_launch(void* const* d_in, const int* in_sizes, int n_in,
                              void* d_out, int out_size, void* d_ws, size_t ws_size,
                              hipStream_t stream) {
  const int* mask = (const int*)d_in[3];
  const float* bq = (const float*)d_in[5];
  const float* bk = (const float*)d_in[7];
  const float* bv = (const float*)d_in[9];
  const float* bo = (const float*)d_in[11];

  const size_t NE = (size_t)B_ * S_ * DM;  // 4M
  const size_t NW = (size_t)DM * DM;       // 1M

  ushort* qc = (ushort*)d_ws;
  ushort* kc = qc + NE;
  ushort* vc = kc + NE;
  ushort* Qp = vc + NE;
  ushort* Kp = Qp + NE;
  ushort* Vt = Kp + NE;
  ushort* Wqc = Vt + NE;
  ushort* Wkc = Wqc + NW;
  ushort* Wvc = Wkc + NW;
  ushort* Woc = Wvc + NW;
  unsigned long long* mbits = (unsigned long long*)d_out;  // 1 MB at head of out

  Cvt7 c;
  const int sidx[7] = {0, 1, 2, 4, 6, 8, 10};
  ushort* dsts[7] = {qc, kc, vc, Wqc, Wkc, Wvc, Woc};
  for (int i = 0; i < 7; ++i) {
    c.src[i] = (const float*)d_in[sidx[i]];
    c.dst[i] = dsts[i];
    c.n[i] = (i < 3) ? (int)NE : (int)NW;
  }
  cvt_all<<<dim3(2048, 8), 256, 0, stream>>>(c, mask, mbits);

  // Q projection pre-scaled by (1/sqrt(dk)) * log2(e) so attn uses exp2
  G3 g;
  g.A[0] = qc;  g.A[1] = kc;  g.A[2] = vc;
  g.W[0] = Wqc; g.W[1] = Wkc; g.W[2] = Wvc;
  g.bias[0] = bq; g.bias[1] = bk; g.bias[2] = bv;
  g.C[0] = Qp;  g.C[1] = Kp;  g.C[2] = Vt;
  g.scale[0] = 0.125f * 1.4426950408889634f;
  g.scale[1] = 1.0f;
  g.scale[2] = 1.0f;
  gemm_qkv<<<dim3(Mdim / 128, Ndim / 128, 3), 256, 0, stream>>>(g);

  attn_mfma<<<dim3(512), 256, 0, stream>>>(Qp, Kp, Vt, mbits, qc);

  gemm128<float><<<dim3(Mdim / 128, Ndim / 64), 256, 0, stream>>>(
      qc, Woc, bo, (float*)d_out, 1.0f);
}